// Round 10
// baseline (373.182 us; speedup 1.0000x reference)
//
#include <hip/hip_runtime.h>
#include <math.h>

#define NN 100000
#define NE 1600000
#define PART_BLOCKS 768
#define NT1 1563          // ceil(NN/64)  M-tiles (gemm1)
#define NT2 782           // ceil(NN/128) M-tiles (gemm2)
#define LDA 136           // padded LDS row stride (ushorts): 272 B, 16B-aligned
#define LDW 264           // padded W2T-full row stride (ushorts): 528 B
#define NMSK 0x1FFFF      // node-index mask (NN < 2^17); bounds derived addrs into ws

// ---- bucketed CSR build params ----
#define NBK 391           // ceil(NN/256) buckets of 256 dst nodes
#define EPB 4096          // edges per hist/part block
#define NPB 391           // ceil(NE/EPB)

typedef float f32x4 __attribute__((ext_vector_type(4)));
typedef float f32x2 __attribute__((ext_vector_type(2)));
typedef short s16x8 __attribute__((ext_vector_type(8)));

union Q16 { uint4 q; s16x8 v; };

// ---- ws layout (4-byte words) ----
#define OFS_BKT   0                     // bkt_cnt[512] | bkt_base[512] | bkt_cur[512] | dcnt[64] | dcur[64]
#define OFS_DEG   (8*NN)                // int[NN]
#define OFS_RP    (9*NN)                // int[NN]
#define OFS_BSUM  (10*NN)               // reused: bias2[128] fp32 (b2l + sh·w2r)
#define OFS_RANK  (10*NN + 1024)        // reused: perm[NN] uint2 {node|deg<<17, rp} -> 2*NN words
#define OFS_CSR   (OFS_RANK + NE/2)
#define OFS_INV   (OFS_CSR + NE)
#define OFS_HAS   (OFS_INV + NN)
#define OFS_XB    (OFS_HAS + NN)        // x bf16 [NN][64]   -> 32*NN words
#define OFS_XB8   (OFS_XB + 32*NN)      // x fp8 [NN][64]    -> 16*NN words
#define OFS_A1B   (OFS_XB8 + 16*NN)     // agg1 bf16 [NN][64]-> 32*NN
#define OFS_H1B   (OFS_A1B + 32*NN)     // h1 bf16 STANDARD cols [NN][128] -> 64*NN
#define OFS_H1F8  (OFS_H1B + 64*NN)     // h1 fp8 PERMUTED [NN][128] -> 32*NN
#define OFS_A2B   (OFS_H1F8 + 32*NN)    // BN'd agg2 bf16 PERMUTED [NN][128] -> 64*NN
                                        //   (also reused EARLY as packed-edge buffer, NE words)
#define OFS_W1T   (OFS_A2B + 64*NN)     // [128][128] ush -> 8192 words
#define OFS_W2T   (OFS_W1T + 8192)      // [128][256] ush (a2b-half K permuted; h1-half K STANDARD, sc-scaled by k_wfix) -> 16384
#define OFS_WFCT  (OFS_W2T + 16384)     // [16][128] ush (K standard) -> 1024 words
#define OFS_STATS (OFS_WFCT + 1024)     // 512: [sc 128][sh 128][sc' 128][sh' 128]
#define OFS_PART  (OFS_STATS + 512)     // 768*256

// col permutation: c' = l15*8 + nt  <->  c = nt*16 + l15  (P(c') = (c'&7)*16 + (c'>>3))
// stats[256+c'] = sc[P(c')], stats[384+c'] = sh[P(c')]

__device__ __forceinline__ unsigned short f2bf(float f) {
    unsigned u = __float_as_uint(f);
    return (unsigned short)((u + 0x7FFFu + ((u >> 16) & 1u)) >> 16);
}
__device__ __forceinline__ float bfl(unsigned u) { return __uint_as_float(u << 16); }
__device__ __forceinline__ float bfh(unsigned u) { return __uint_as_float(u & 0xFFFF0000u); }

// ---- fp8 e4m3 pack/unpack (HW cvt on gfx950; software fallback) ----
#if __has_builtin(__builtin_amdgcn_cvt_pk_f32_fp8) && __has_builtin(__builtin_amdgcn_cvt_pk_fp8_f32)
__device__ __forceinline__ f32x2 cvt2_lo(unsigned w) {
    return __builtin_amdgcn_cvt_pk_f32_fp8((int)w, false);
}
__device__ __forceinline__ f32x2 cvt2_hi(unsigned w) {
    return __builtin_amdgcn_cvt_pk_f32_fp8((int)w, true);
}
__device__ __forceinline__ unsigned pk_fp8x4(float a, float b, float c, float d) {
    int w = __builtin_amdgcn_cvt_pk_fp8_f32(a, b, 0, false);
    w = __builtin_amdgcn_cvt_pk_fp8_f32(c, d, w, true);
    return (unsigned)w;
}
#else
__device__ __forceinline__ float sw_fp82f(unsigned v) {
    unsigned s = (v & 0x80u) << 24;
    unsigned e = (v >> 3) & 15u, m = v & 7u;
    float r = (e == 0) ? ((float)m * 0.001953125f)
                       : __uint_as_float(((e + 120u) << 23) | (m << 20));
    return __uint_as_float(s | __float_as_uint(r));
}
__device__ __forceinline__ f32x2 cvt2_lo(unsigned w) {
    return (f32x2){sw_fp82f(w & 255u), sw_fp82f((w >> 8) & 255u)};
}
__device__ __forceinline__ f32x2 cvt2_hi(unsigned w) {
    return (f32x2){sw_fp82f((w >> 16) & 255u), sw_fp82f(w >> 24)};
}
__device__ __forceinline__ unsigned sw_f2fp8(float f) {
    unsigned b = __float_as_uint(f);
    unsigned s = (b >> 24) & 0x80u;
    float af = fabsf(f);
    if (af < 0.0009765625f) return s;
    if (af >= 448.f) return s | 0x7Eu;
    int e = (int)((b >> 23) & 255u) - 127;
    if (e < -6) {
        int q = (int)rintf(af * 512.f);
        return s | (unsigned)q;
    }
    unsigned man = b & 0x7FFFFFu;
    unsigned r = (man + 0x7FFFFu + ((man >> 20) & 1u)) >> 20;
    unsigned enc = ((unsigned)(e + 7) << 3) + r;
    if (enc >= 0x7Fu) enc = 0x7Eu;
    return s | enc;
}
__device__ __forceinline__ unsigned pk_fp8x4(float a, float b, float c, float d) {
    return sw_f2fp8(a) | (sw_f2fp8(b) << 8) | (sw_f2fp8(c) << 16) | (sw_f2fp8(d) << 24);
}
#endif

// ---------------- init: cast x -> bf16+fp8, weights -> transposed bf16 ----------------
#define CAST_BLOCKS 6250   // NN*16/256
#define PREP_BLOCKS 200    // (16384+32768+2048)/256
__global__ void k_init(const float4* __restrict__ x4, uint2* __restrict__ xb,
                       unsigned* __restrict__ xb8,
                       const float* __restrict__ w1l, const float* __restrict__ w1r,
                       const float* __restrict__ w2l, const float* __restrict__ w2r,
                       const float* __restrict__ wfc,
                       unsigned short* __restrict__ W1T, unsigned short* __restrict__ W2T,
                       unsigned short* __restrict__ wfcT) {
    int b = blockIdx.x, t = threadIdx.x;
    if (b < CAST_BLOCKS) {
        int i = b * 256 + t;
        float4 v = x4[i];
        uint2 o;
        o.x = (unsigned)f2bf(v.x) | ((unsigned)f2bf(v.y) << 16);
        o.y = (unsigned)f2bf(v.z) | ((unsigned)f2bf(v.w) << 16);
        xb[i] = o;
        xb8[i] = pk_fp8x4(v.x, v.y, v.z, v.w);
        return;
    }
    int u = (b - CAST_BLOCKS) * 256 + t;
    if (u < 16384) {
        int n = u >> 7, k = u & 127;
        float v = (k < 64) ? w1l[k * 128 + n] : w1r[(k - 64) * 128 + n];
        W1T[u] = f2bf(v);
    } else if (u < 16384 + 32768) {
        int u2 = u - 16384;
        int n = u2 >> 8, kk = u2 & 255;
        float v;
        if (kk < 128) {
            int pk = (kk & 7) * 16 + (kk >> 3);   // permuted lin_l K-row (matches a2b)
            v = w2l[pk * 128 + n];
        } else {
            v = w2r[(kk - 128) * 128 + n];        // STANDARD K (matches std h1b; k_wfix rescales)
        }
        W2T[u2] = f2bf(v);
    } else {
        int u3 = u - 16384 - 32768;
        int o = u3 >> 7, k = u3 & 127;
        wfcT[u3] = f2bf(wfc[k * 16 + o]);         // standard K (Asm holds std cols)
    }
}

// ---------------- CSR build: bucketed counting sort (no global per-edge atomics) ----
__global__ __launch_bounds__(256) void k_hist(const int* __restrict__ ei,
                                              int* __restrict__ bkt_cnt) {
    __shared__ int lc[NBK];
    int t = threadIdx.x;
    for (int i = t; i < NBK; i += 256) lc[i] = 0;
    __syncthreads();
    int e0 = blockIdx.x * EPB;
    int e1 = e0 + EPB; if (e1 > NE) e1 = NE;
    for (int e = e0 + t; e < e1; e += 256) {
        int d = ei[NE + e];
        atomicAdd(&lc[d >> 8], 1);
    }
    __syncthreads();
    for (int i = t; i < NBK; i += 256)
        if (lc[i]) atomicAdd(&bkt_cnt[i], lc[i]);
}

__global__ void k_bscan(const int* __restrict__ cnt, int* __restrict__ base,
                        int* __restrict__ cur) {
    __shared__ int s[512];
    int t = threadIdx.x;
    int v = (t < NBK) ? cnt[t] : 0;
    s[t] = v;
    __syncthreads();
    for (int o = 1; o < 512; o <<= 1) {
        int u = (t >= o) ? s[t - o] : 0;
        __syncthreads();
        s[t] += u;
        __syncthreads();
    }
    if (t < NBK) {
        int b = s[t] - v;
        base[t] = b;
        cur[t] = b;
        if (t == NBK - 1) base[NBK] = s[t];   // == NE
    }
}

__global__ __launch_bounds__(256) void k_part(const int* __restrict__ ei,
                                              int* __restrict__ bkt_cur,
                                              unsigned* __restrict__ packed) {
    __shared__ int lc[NBK];
    __shared__ int gb[NBK];
    int t = threadIdx.x;
    for (int i = t; i < NBK; i += 256) lc[i] = 0;
    __syncthreads();
    int e0 = blockIdx.x * EPB;
    int e1 = e0 + EPB; if (e1 > NE) e1 = NE;
    for (int e = e0 + t; e < e1; e += 256) {
        int d = ei[NE + e];
        atomicAdd(&lc[d >> 8], 1);
    }
    __syncthreads();
    for (int i = t; i < NBK; i += 256) {
        int c = lc[i];
        gb[i] = c ? atomicAdd(&bkt_cur[i], c) : 0;  // reserve per-(block,bucket) range
        lc[i] = 0;
    }
    __syncthreads();
    for (int e = e0 + t; e < e1; e += 256) {
        int d = ei[NE + e];
        int s = ei[e];
        int b = d >> 8;
        int r = atomicAdd(&lc[b], 1);               // local rank (LDS)
        packed[gb[b] + r] = (unsigned)s | ((unsigned)(d & 255) << 17);
    }
}

__global__ __launch_bounds__(256) void k_bucket(const unsigned* __restrict__ packed,
                                                const int* __restrict__ bkt_base,
                                                int* __restrict__ csr, int* __restrict__ deg,
                                                int* __restrict__ rp,
                                                int* __restrict__ dcnt) {
    __shared__ int cnt[256];
    __shared__ int off[256];
    __shared__ int dh[64];
    int b = blockIdx.x, t = threadIdx.x;
    int base = bkt_base[b], end = bkt_base[b + 1];
    cnt[t] = 0;
    if (t < 64) dh[t] = 0;
    __syncthreads();
    for (int i = base + t; i < end; i += 256) {
        unsigned u = packed[i];
        atomicAdd(&cnt[u >> 17], 1);
    }
    __syncthreads();
    int v = cnt[t];
    int node = b * 256 + t;
    if (node < NN) atomicAdd(&dh[v < 63 ? v : 63], 1);
    off[t] = v;
    __syncthreads();
    for (int o = 1; o < 256; o <<= 1) {
        int u = (t >= o) ? off[t - o] : 0;
        __syncthreads();
        off[t] += u;
        __syncthreads();
    }
    int excl = off[t] - v;                 // exclusive prefix within bucket
    if (node < NN) {
        deg[node] = v;
        rp[node] = base + excl;
    }
    cnt[t] = base + excl;                  // reuse as scatter cursor
    __syncthreads();
    for (int i = base + t; i < end; i += 256) {
        unsigned u = packed[i];
        int p = atomicAdd(&cnt[u >> 17], 1);
        csr[p] = (int)(u & 0x1FFFFu);
    }
    if (t < 64 && dh[t]) atomicAdd(&dcnt[t], dh[t]);
}

__global__ void k_dscan(const int* __restrict__ dcnt, int* __restrict__ dcur) {
    __shared__ int s[64];
    int t = threadIdx.x;
    int v = dcnt[t];
    s[t] = v;
    __syncthreads();
    for (int o = 1; o < 64; o <<= 1) {
        int u = (t >= o) ? s[t - o] : 0;
        __syncthreads();
        s[t] += u;
        __syncthreads();
    }
    dcur[t] = s[t] - v;
}

__global__ __launch_bounds__(256) void k_dperm(const int* __restrict__ deg,
                                               const int* __restrict__ rp,
                                               int* __restrict__ dcur,
                                               uint2* __restrict__ perm) {
    __shared__ int lc[64];
    __shared__ int gb[64];
    int t = threadIdx.x;
    if (t < 64) lc[t] = 0;
    __syncthreads();
    int node = blockIdx.x * 256 + t;
    int bin = 0, r = 0, d = 0;
    bool ok = node < NN;
    if (ok) {
        d = deg[node];
        bin = d < 63 ? d : 63;
        r = atomicAdd(&lc[bin], 1);
    }
    __syncthreads();
    if (t < 64) gb[t] = lc[t] ? atomicAdd(&dcur[t], lc[t]) : 0;
    __syncthreads();
    if (ok) perm[gb[bin] + r] = make_uint2((unsigned)node | ((unsigned)d << 17),
                                           (unsigned)rp[node]);
}

// ---------------- gather layer 1 (fp8): agg1b[n] = bf16(mean x[s]) ----------------
__global__ __launch_bounds__(256) void k_agg1(
    const uint4* __restrict__ xb8, const int* __restrict__ csr,
    const uint2* __restrict__ perm, uint4* __restrict__ agg1b) {
    int t = threadIdx.x;
    int lane = t & 63;
    int grp = lane >> 2, f = lane & 3;
    int slot = blockIdx.x * 64 + (t >> 6) * 16 + grp;
    bool ok = slot < NN;
    uint2 pn = ok ? perm[slot] : make_uint2(0u, 0u);
    int node = (int)(pn.x & NMSK);
    int len = ok ? (int)(pn.x >> 17) : 0;
    const int* cp = csr + pn.y;
    f32x2 c[8];
#pragma unroll
    for (int k = 0; k < 8; k++) c[k] = (f32x2){0.f, 0.f};
    int s0 = cp[0] & NMSK, s1 = cp[1] & NMSK, s2 = cp[2] & NMSK, s3 = cp[3] & NMSK;
    int j = 0;
    while (j + 3 < len) {
        int n0 = cp[j + 4] & NMSK, n1 = cp[j + 5] & NMSK;
        int n2 = cp[j + 6] & NMSK, n3 = cp[j + 7] & NMSK;
        uint4 u0 = xb8[s0 * 4 + f];
        uint4 u1 = xb8[s1 * 4 + f];
        uint4 u2 = xb8[s2 * 4 + f];
        uint4 u3 = xb8[s3 * 4 + f];
        c[0] += cvt2_lo(u0.x); c[1] += cvt2_hi(u0.x); c[2] += cvt2_lo(u0.y); c[3] += cvt2_hi(u0.y);
        c[4] += cvt2_lo(u0.z); c[5] += cvt2_hi(u0.z); c[6] += cvt2_lo(u0.w); c[7] += cvt2_hi(u0.w);
        c[0] += cvt2_lo(u1.x); c[1] += cvt2_hi(u1.x); c[2] += cvt2_lo(u1.y); c[3] += cvt2_hi(u1.y);
        c[4] += cvt2_lo(u1.z); c[5] += cvt2_hi(u1.z); c[6] += cvt2_lo(u1.w); c[7] += cvt2_hi(u1.w);
        c[0] += cvt2_lo(u2.x); c[1] += cvt2_hi(u2.x); c[2] += cvt2_lo(u2.y); c[3] += cvt2_hi(u2.y);
        c[4] += cvt2_lo(u2.z); c[5] += cvt2_hi(u2.z); c[6] += cvt2_lo(u2.w); c[7] += cvt2_hi(u2.w);
        c[0] += cvt2_lo(u3.x); c[1] += cvt2_hi(u3.x); c[2] += cvt2_lo(u3.y); c[3] += cvt2_hi(u3.y);
        c[4] += cvt2_lo(u3.z); c[5] += cvt2_hi(u3.z); c[6] += cvt2_lo(u3.w); c[7] += cvt2_hi(u3.w);
        j += 4; s0 = n0; s1 = n1; s2 = n2; s3 = n3;
    }
    while (j < len) {
        uint4 u = xb8[s0 * 4 + f];
        c[0] += cvt2_lo(u.x); c[1] += cvt2_hi(u.x); c[2] += cvt2_lo(u.y); c[3] += cvt2_hi(u.y);
        c[4] += cvt2_lo(u.z); c[5] += cvt2_hi(u.z); c[6] += cvt2_lo(u.w); c[7] += cvt2_hi(u.w);
        s0 = s1; s1 = s2; s2 = s3; ++j;
    }
    float ic = 1.0f / fmaxf((float)len, 1.0f);
    uint4 o0, o1;
    o0.x = (unsigned)f2bf(c[0][0] * ic) | ((unsigned)f2bf(c[0][1] * ic) << 16);
    o0.y = (unsigned)f2bf(c[1][0] * ic) | ((unsigned)f2bf(c[1][1] * ic) << 16);
    o0.z = (unsigned)f2bf(c[2][0] * ic) | ((unsigned)f2bf(c[2][1] * ic) << 16);
    o0.w = (unsigned)f2bf(c[3][0] * ic) | ((unsigned)f2bf(c[3][1] * ic) << 16);
    o1.x = (unsigned)f2bf(c[4][0] * ic) | ((unsigned)f2bf(c[4][1] * ic) << 16);
    o1.y = (unsigned)f2bf(c[5][0] * ic) | ((unsigned)f2bf(c[5][1] * ic) << 16);
    o1.z = (unsigned)f2bf(c[6][0] * ic) | ((unsigned)f2bf(c[6][1] * ic) << 16);
    o1.w = (unsigned)f2bf(c[7][0] * ic) | ((unsigned)f2bf(c[7][1] * ic) << 16);
    if (ok) {
        agg1b[node * 8 + f * 2] = o0;
        agg1b[node * 8 + f * 2 + 1] = o1;
    }
}

// ---------------- gather layer 2 (fp8, permuted cols) + BN fold ----------------
__global__ __launch_bounds__(256) void k_agg2(
    const uint4* __restrict__ h1f8, const int* __restrict__ csr,
    const float* __restrict__ statsp, const uint2* __restrict__ perm,
    uint4* __restrict__ a2b) {
    int t = threadIdx.x;
    int lane = t & 63;
    int grp = lane >> 3, f = lane & 7;
    int slot = blockIdx.x * 32 + (t >> 6) * 8 + grp;   // NN % 32 == 0
    uint2 pn = perm[slot];
    int node = (int)(pn.x & NMSK);
    int len = (int)(pn.x >> 17);
    const int* cp = csr + pn.y;
    f32x2 c[8];
#pragma unroll
    for (int k = 0; k < 8; k++) c[k] = (f32x2){0.f, 0.f};
    int s0 = cp[0] & NMSK, s1 = cp[1] & NMSK, s2 = cp[2] & NMSK, s3 = cp[3] & NMSK;
    int j = 0;
    while (j + 3 < len) {
        int n0 = cp[j + 4] & NMSK, n1 = cp[j + 5] & NMSK;
        int n2 = cp[j + 6] & NMSK, n3 = cp[j + 7] & NMSK;
        uint4 u0 = h1f8[s0 * 8 + f];
        uint4 u1 = h1f8[s1 * 8 + f];
        uint4 u2 = h1f8[s2 * 8 + f];
        uint4 u3 = h1f8[s3 * 8 + f];
        c[0] += cvt2_lo(u0.x); c[1] += cvt2_hi(u0.x); c[2] += cvt2_lo(u0.y); c[3] += cvt2_hi(u0.y);
        c[4] += cvt2_lo(u0.z); c[5] += cvt2_hi(u0.z); c[6] += cvt2_lo(u0.w); c[7] += cvt2_hi(u0.w);
        c[0] += cvt2_lo(u1.x); c[1] += cvt2_hi(u1.x); c[2] += cvt2_lo(u1.y); c[3] += cvt2_hi(u1.y);
        c[4] += cvt2_lo(u1.z); c[5] += cvt2_hi(u1.z); c[6] += cvt2_lo(u1.w); c[7] += cvt2_hi(u1.w);
        c[0] += cvt2_lo(u2.x); c[1] += cvt2_hi(u2.x); c[2] += cvt2_lo(u2.y); c[3] += cvt2_hi(u2.y);
        c[4] += cvt2_lo(u2.z); c[5] += cvt2_hi(u2.z); c[6] += cvt2_lo(u2.w); c[7] += cvt2_hi(u2.w);
        c[0] += cvt2_lo(u3.x); c[1] += cvt2_hi(u3.x); c[2] += cvt2_lo(u3.y); c[3] += cvt2_hi(u3.y);
        c[4] += cvt2_lo(u3.z); c[5] += cvt2_hi(u3.z); c[6] += cvt2_lo(u3.w); c[7] += cvt2_hi(u3.w);
        j += 4; s0 = n0; s1 = n1; s2 = n2; s3 = n3;
    }
    while (j < len) {
        uint4 u = h1f8[s0 * 8 + f];
        c[0] += cvt2_lo(u.x); c[1] += cvt2_hi(u.x); c[2] += cvt2_lo(u.y); c[3] += cvt2_hi(u.y);
        c[4] += cvt2_lo(u.z); c[5] += cvt2_hi(u.z); c[6] += cvt2_lo(u.w); c[7] += cvt2_hi(u.w);
        s0 = s1; s1 = s2; s2 = s3; ++j;
    }
    float ic = 1.0f / fmaxf((float)len, 1.0f);
    float hv = (len > 0) ? 1.0f : 0.0f;
    const float4* sc4 = (const float4*)statsp;
    const float4* sh4 = (const float4*)(statsp + 128);
    float v[16];
#pragma unroll
    for (int q = 0; q < 4; q++) {
        float4 sc = sc4[f * 4 + q];
        float4 sh = sh4[f * 4 + q];
        v[q * 4 + 0] = c[q * 2][0] * ic * sc.x + sh.x * hv;
        v[q * 4 + 1] = c[q * 2][1] * ic * sc.y + sh.y * hv;
        v[q * 4 + 2] = c[q * 2 + 1][0] * ic * sc.z + sh.z * hv;
        v[q * 4 + 3] = c[q * 2 + 1][1] * ic * sc.w + sh.w * hv;
    }
    uint4 o0, o1;
    o0.x = (unsigned)f2bf(v[0]) | ((unsigned)f2bf(v[1]) << 16);
    o0.y = (unsigned)f2bf(v[2]) | ((unsigned)f2bf(v[3]) << 16);
    o0.z = (unsigned)f2bf(v[4]) | ((unsigned)f2bf(v[5]) << 16);
    o0.w = (unsigned)f2bf(v[6]) | ((unsigned)f2bf(v[7]) << 16);
    o1.x = (unsigned)f2bf(v[8]) | ((unsigned)f2bf(v[9]) << 16);
    o1.y = (unsigned)f2bf(v[10]) | ((unsigned)f2bf(v[11]) << 16);
    o1.z = (unsigned)f2bf(v[12]) | ((unsigned)f2bf(v[13]) << 16);
    o1.w = (unsigned)f2bf(v[14]) | ((unsigned)f2bf(v[15]) << 16);
    a2b[node * 16 + f * 2] = o0;
    a2b[node * 16 + f * 2 + 1] = o1;
}

// ---------------- layer 1 MFMA: A direct, W staged once; per-tile barriers REMOVED
// (Asm rows [16w,16w+16) are wave-private: epilogue writer rows 16w+quad*4+r and
// readback rows t>>2 both lie in wave w's slice; same-wave DS ops are ordered) ----
__global__ __launch_bounds__(256, 3) void k_gemm1(
    const uint4* __restrict__ agg1b, const uint4* __restrict__ xb,
    const uint4* __restrict__ W1T, const float* __restrict__ b1l,
    uint4* __restrict__ h1b, uint2* __restrict__ h1f8, float* __restrict__ part) {
    __shared__ unsigned short Wsm[128 * LDA];  // 34816 B
    __shared__ unsigned short Asm[64 * LDA];   // 17408 B
    __shared__ float cs[128], cq[128];
    const int t = threadIdx.x;
    const int w = t >> 6, lane = t & 63, quad = lane >> 4, l15 = lane & 15;
    if (t < 128) { cs[t] = 0.f; cq[t] = 0.f; }
    {   // stage W1T once (row=256B=16 uint4)
        int r = t >> 1, h = t & 1;
#pragma unroll
        for (int i = 0; i < 8; i++) {
            uint4 v = W1T[r * 16 + h * 8 + i];
            *(uint4*)&Wsm[r * LDA + h * 64 + i * 8] = v;
        }
    }
    float bias[8];
#pragma unroll
    for (int nt = 0; nt < 8; nt++) bias[nt] = b1l[nt * 16 + l15];
    float colsum[8] = {0, 0, 0, 0, 0, 0, 0, 0};
    float colsq[8]  = {0, 0, 0, 0, 0, 0, 0, 0};
    const int arow = 16 * w + l15;          // this lane's A-fragment row
    __syncthreads();                        // W staged, cs/cq init (cross-wave, keep)

    for (int g = blockIdx.x; g < NT1; g += gridDim.x) {
        const int base = g * 64;
        const int valid = (NN - base < 64) ? (NN - base) : 64;
        const int gm = base + arow;
        const bool okA = arow < valid;
        Q16 af[4];
#pragma unroll
        for (int kc = 0; kc < 2; kc++)
            af[kc].q = okA ? agg1b[gm * 8 + kc * 4 + quad] : make_uint4(0, 0, 0, 0);
#pragma unroll
        for (int kc = 0; kc < 2; kc++)
            af[2 + kc].q = okA ? xb[gm * 8 + kc * 4 + quad] : make_uint4(0, 0, 0, 0);
        f32x4 acc[8];
#pragma unroll
        for (int nt = 0; nt < 8; nt++) acc[nt] = (f32x4){bias[nt], bias[nt], bias[nt], bias[nt]};
#pragma unroll
        for (int kc = 0; kc < 4; kc++) {
#pragma unroll
            for (int nt = 0; nt < 8; nt++) {
                s16x8 bf = *(const s16x8*)&Wsm[(nt * 16 + l15) * LDA + kc * 32 + quad * 8];
                acc[nt] = __builtin_amdgcn_mfma_f32_16x16x32_bf16(af[kc].v, bf, acc[nt], 0, 0, 0);
            }
        }
        // epilogue: norm+relu+stats; bf16 into Asm (std cols); fp8 direct (permuted)
        float ssr[4] = {0, 0, 0, 0};
#pragma unroll
        for (int nt = 0; nt < 8; nt++)
#pragma unroll
            for (int r = 0; r < 4; r++) ssr[r] += acc[nt][r] * acc[nt][r];
#pragma unroll
        for (int r = 0; r < 4; r++) {
            ssr[r] += __shfl_xor(ssr[r], 1); ssr[r] += __shfl_xor(ssr[r], 2);
            ssr[r] += __shfl_xor(ssr[r], 4); ssr[r] += __shfl_xor(ssr[r], 8);
        }
#pragma unroll
        for (int r = 0; r < 4; r++) {
            int mrow = 16 * w + quad * 4 + r;
            float iv = 1.0f / fmaxf(sqrtf(ssr[r]), 1e-12f);
            bool okr = mrow < valid;
            float v[8];
#pragma unroll
            for (int nt = 0; nt < 8; nt++) {
                float vv = fmaxf(acc[nt][r] * iv, 0.f);
                if (!okr) vv = 0.f;
                v[nt] = vv;
                colsum[nt] += vv;
                colsq[nt] += vv * vv;
                Asm[mrow * LDA + nt * 16 + l15] = f2bf(vv);
            }
            if (okr) {
                uint2 o;
                o.x = pk_fp8x4(v[0], v[1], v[2], v[3]);
                o.y = pk_fp8x4(v[4], v[5], v[6], v[7]);
                h1f8[(base + mrow) * 16 + l15] = o;   // permuted col' = l15*8+nt
            }
        }
        // (no barrier: wave-private Asm slice)
        {   // coalesced h1b store (row=256B=16 uint4), STANDARD layout
            int m = t >> 2, p = t & 3;
            if (m < valid) {
                int gm2 = base + m;
#pragma unroll
                for (int i = 0; i < 4; i++) {
                    uint4 v = *(const uint4*)&Asm[m * LDA + p * 32 + i * 8];
                    h1b[gm2 * 16 + p * 4 + i] = v;
                }
            }
        }
        // (no barrier: next tile's writes are same-wave ordered after these reads)
    }
    __syncthreads();
#pragma unroll
    for (int nt = 0; nt < 8; nt++) {
        atomicAdd(&cs[nt * 16 + l15], colsum[nt]);
        atomicAdd(&cq[nt * 16 + l15], colsq[nt]);
    }
    __syncthreads();
    if (t < 128) {
        part[blockIdx.x * 256 + t] = cs[t];
        part[blockIdx.x * 256 + 128 + t] = cq[t];
    }
}

// ---------------- BN finalize: stats + permuted copy ----------------
__global__ void k_bnfin(const float* __restrict__ part, const float* __restrict__ gamma,
                        const float* __restrict__ beta, float* __restrict__ stats) {
    int t = threadIdx.x;  // 128 (channel)
    float s = 0.f, q = 0.f;
    for (int b = 0; b < PART_BLOCKS; b++) {
        s += part[b * 256 + t];
        q += part[b * 256 + 128 + t];
    }
    float mean = s / (float)NN;
    float var = q / (float)NN - mean * mean;
    float sc = gamma[t] * rsqrtf(var + 1e-5f);
    float sh = beta[t] - mean * sc;
    stats[t] = sc;
    stats[128 + t] = sh;
    int cp = (t & 15) * 8 + (t >> 4);   // permuted position of channel t
    stats[256 + cp] = sc;
    stats[384 + cp] = sh;
}

// ---------------- W2 fixup: fold BN scale into lin_r weights, shift into bias ----
// (sc*h1+sh) @ w2r == h1 @ (diag(sc)·w2r) + sh·w2r.  STANDARD K positions.
__global__ void k_wfix(const float* __restrict__ w2r, const float* __restrict__ stats,
                       const float* __restrict__ b2l,
                       unsigned short* __restrict__ W2T, float* __restrict__ bias2) {
    __shared__ float sb[128];
    int n = blockIdx.x;       // 128 (output channel)
    int k = threadIdx.x;      // 128 (std K position = h1 channel)
    float wv = w2r[k * 128 + n];
    W2T[n * 256 + 128 + k] = f2bf(wv * stats[k]);
    sb[k] = stats[128 + k] * wv;                    // sh[k] * w2r[k][n]
    __syncthreads();
    for (int o = 64; o > 0; o >>= 1) {
        if (k < o) sb[k] += sb[k + o];
        __syncthreads();
    }
    if (k == 0) bias2[n] = b2l[n] + sb[0];
}

// ---------------- layer 2 MFMA (K=256) + L2norm + FC; per-tile barriers REMOVED
// (FC reads Asm row 16w+l15 — wave w's own rows; same-wave DS ops are ordered) ----
__global__ __launch_bounds__(512) void k_gemm2(
    const uint4* __restrict__ a2b, const uint4* __restrict__ h1b,
    const uint4* __restrict__ W2T, const float* __restrict__ bias2,
    const uint4* __restrict__ wfcT, const float* __restrict__ bfc,
    float* __restrict__ out) {
    __shared__ unsigned short WsmF[128 * LDW];   // 67584 B (full W2T [N=128][K=256])
    __shared__ unsigned short Asm[128 * LDA];    // 34816 B (h2 for FC redistribution)
    __shared__ unsigned short wfcsm[16 * LDA];   // 4352 B
    const int t = threadIdx.x;
    const int w = t >> 6, lane = t & 63, quad = lane >> 4, l15 = lane & 15;

    {   // full W2T: row r (N), 512B = 32 uint4
        int r = t >> 2, seg = t & 3;
#pragma unroll
        for (int i = 0; i < 8; i++) {
            uint4 v = W2T[r * 32 + seg * 8 + i];
            *(uint4*)&WsmF[r * LDW + (seg * 8 + i) * 8] = v;
        }
    }
    if (t < 64) {   // wfcT: 16 rows x 256B
        int n = t >> 2, p = t & 3;
#pragma unroll
        for (int i = 0; i < 4; i++) {
            uint4 v = wfcT[n * 16 + p * 4 + i];
            *(uint4*)&wfcsm[n * LDA + p * 32 + i * 8] = v;
        }
    }
    float bias[8];
#pragma unroll
    for (int nt = 0; nt < 8; nt++) bias[nt] = bias2[nt * 16 + l15];
    const float fb = bfc[l15];
    const int arow = 16 * w + l15;          // 0..127
    __syncthreads();                        // W/wfc staged (cross-wave, keep)

    for (int g = blockIdx.x; g < NT2; g += gridDim.x) {
        const int base = g * 128;
        const int valid = (NN - base < 128) ? (NN - base) : 128;
        const int gm = base + arow;
        const bool okA = arow < valid;

        Q16 af[8];
#pragma unroll
        for (int kc = 0; kc < 4; kc++)
            af[kc].q = okA ? a2b[gm * 16 + kc * 4 + quad] : make_uint4(0, 0, 0, 0);
#pragma unroll
        for (int kc = 0; kc < 4; kc++)
            af[4 + kc].q = okA ? h1b[gm * 16 + kc * 4 + quad] : make_uint4(0, 0, 0, 0);

        f32x4 acc[8];
#pragma unroll
        for (int nt = 0; nt < 8; nt++) acc[nt] = (f32x4){bias[nt], bias[nt], bias[nt], bias[nt]};
#pragma unroll
        for (int kc = 0; kc < 8; kc++) {
#pragma unroll
            for (int nt = 0; nt < 8; nt++) {
                s16x8 bf = *(const s16x8*)&WsmF[(nt * 16 + l15) * LDW + kc * 32 + quad * 8];
                acc[nt] = __builtin_amdgcn_mfma_f32_16x16x32_bf16(af[kc].v, bf, acc[nt], 0, 0, 0);
            }
        }

        // epilogue: L2 norm, h2 -> Asm (standard col positions, wave-private rows)
        float ssr[4] = {0, 0, 0, 0};
#pragma unroll
        for (int nt = 0; nt < 8; nt++)
#pragma unroll
            for (int r = 0; r < 4; r++) ssr[r] += acc[nt][r] * acc[nt][r];
#pragma unroll
        for (int r = 0; r < 4; r++) {
            ssr[r] += __shfl_xor(ssr[r], 1); ssr[r] += __shfl_xor(ssr[r], 2);
            ssr[r] += __shfl_xor(ssr[r], 4); ssr[r] += __shfl_xor(ssr[r], 8);
        }
#pragma unroll
        for (int r = 0; r < 4; r++) {
            int mrow = 16 * w + quad * 4 + r;
            float iv = 1.0f / fmaxf(sqrtf(ssr[r]), 1e-12f);
#pragma unroll
            for (int nt = 0; nt < 8; nt++) {
                Asm[mrow * LDA + nt * 16 + l15] = f2bf(acc[nt][r] * iv);
            }
        }
        // (no barrier: FC reads only wave w's rows)
        // FC: 16x16 tile per wave, K=128
        f32x4 a2 = (f32x4){fb, fb, fb, fb};
#pragma unroll
        for (int kc = 0; kc < 4; kc++) {
            s16x8 af2 = *(const s16x8*)&Asm[arow * LDA + kc * 32 + quad * 8];
            s16x8 bf2 = *(const s16x8*)&wfcsm[l15 * LDA + kc * 32 + quad * 8];
            a2 = __builtin_amdgcn_mfma_f32_16x16x32_bf16(af2, bf2, a2, 0, 0, 0);
        }
#pragma unroll
        for (int r = 0; r < 4; r++) {
            int mrow = 16 * w + quad * 4 + r;
            if (mrow < valid) out[(base + mrow) * 16 + l15] = a2[r];
        }
        // (no barrier: next tile's Asm writes are same-wave ordered after these reads)
    }
}

extern "C" void kernel_launch(void* const* d_in, const int* in_sizes, int n_in,
                              void* d_out, int out_size, void* d_ws, size_t ws_size,
                              hipStream_t stream) {
    const float* x     = (const float*)d_in[0];
    const int*   ei    = (const int*)d_in[1];
    const float* w1l   = (const float*)d_in[2];
    const float* b1l   = (const float*)d_in[3];
    const float* w1r   = (const float*)d_in[4];
    const float* gamma = (const float*)d_in[5];
    const float* beta  = (const float*)d_in[6];
    const float* w2l   = (const float*)d_in[7];
    const float* b2l   = (const float*)d_in[8];
    const float* w2r   = (const float*)d_in[9];
    const float* wfc   = (const float*)d_in[10];
    const float* bfc   = (const float*)d_in[11];
    float* out = (float*)d_out;

    float* W = (float*)d_ws;
    int* bkt_cnt  = (int*)(W + OFS_BKT);          // [512]
    int* bkt_base = bkt_cnt + 512;                // [512] (uses index NBK)
    int* bkt_cur  = bkt_cnt + 1024;               // [512]
    int* dcnt     = bkt_cnt + 1536;               // [64]
    int* dcur     = bkt_cnt + 1600;               // [64]
    int* deg   = (int*)(W + OFS_DEG);
    int* rp    = (int*)(W + OFS_RP);
    float* bias2 = W + OFS_BSUM;                  // [128] fp32
    uint2* perm = (uint2*)(W + OFS_RANK);         // 2*NN words (fat records)
    int* csr   = (int*)(W + OFS_CSR);
    unsigned* xb   = (unsigned*)(W + OFS_XB);
    unsigned* xb8  = (unsigned*)(W + OFS_XB8);
    unsigned* a1b  = (unsigned*)(W + OFS_A1B);
    unsigned* h1b  = (unsigned*)(W + OFS_H1B);
    unsigned* h1f8 = (unsigned*)(W + OFS_H1F8);
    unsigned* a2b  = (unsigned*)(W + OFS_A2B);
    unsigned* packed = (unsigned*)(W + OFS_A2B);  // NE words; dead before k_agg2 writes a2b
    unsigned short* W1T  = (unsigned short*)(W + OFS_W1T);
    unsigned short* W2T  = (unsigned short*)(W + OFS_W2T);
    unsigned short* wfcT = (unsigned short*)(W + OFS_WFCT);
    float* stats = W + OFS_STATS;          // [sc|sh|sc'|sh'] (512)
    float* part  = W + OFS_PART;

    hipMemsetAsync(bkt_cnt, 0, 1664 * sizeof(int), stream);

    k_init<<<CAST_BLOCKS + PREP_BLOCKS, 256, 0, stream>>>(
        (const float4*)x, (uint2*)xb, xb8, w1l, w1r, w2l, w2r, wfc, W1T, W2T, wfcT);
    k_hist  <<<NPB, 256, 0, stream>>>(ei, bkt_cnt);
    k_bscan <<<1, 512, 0, stream>>>(bkt_cnt, bkt_base, bkt_cur);
    k_part  <<<NPB, 256, 0, stream>>>(ei, bkt_cur, packed);
    k_bucket<<<NBK, 256, 0, stream>>>(packed, bkt_base, csr, deg, rp, dcnt);
    k_dscan <<<1, 64, 0, stream>>>(dcnt, dcur);
    k_dperm <<<NBK, 256, 0, stream>>>(deg, rp, dcur, perm);

    k_agg1 <<<(NN + 63) / 64, 256, 0, stream>>>((const uint4*)xb8, csr, perm, (uint4*)a1b);
    k_gemm1<<<PART_BLOCKS, 256, 0, stream>>>((const uint4*)a1b, (const uint4*)xb,
                                             (const uint4*)W1T, b1l, (uint4*)h1b,
                                             (uint2*)h1f8, part);
    k_bnfin<<<1, 128, 0, stream>>>(part, gamma, beta, stats);
    k_wfix <<<128, 128, 0, stream>>>(w2r, stats, b2l, W2T, bias2);
    k_agg2 <<<NN / 32, 256, 0, stream>>>((const uint4*)h1f8, csr, stats + 256, perm,
                                         (uint4*)a2b);
    k_gemm2<<<256, 512, 0, stream>>>((const uint4*)a2b, (const uint4*)h1b,
                                     (const uint4*)W2T, bias2, (const uint4*)wfcT,
                                     bfc, out);
}

// Round 11
// 307.416 us; speedup vs baseline: 1.2139x; 1.2139x over previous
//
#include <hip/hip_runtime.h>
#include <math.h>

#define NN 100000
#define NE 1600000
#define PART_BLOCKS 768
#define NT1 1563          // ceil(NN/64)  M-tiles (gemm1)
#define NT2 782           // ceil(NN/128) M-tiles (gemm2)
#define LDA 136           // padded LDS row stride (ushorts): 272 B, 16B-aligned
#define LDW 264           // padded W2T-full row stride (ushorts): 528 B
#define NMSK 0x1FFFF      // node-index mask (NN < 2^17); bounds derived addrs into ws

// ---- bucketed CSR build params ----
#define NBK 391           // ceil(NN/256) buckets of 256 dst nodes
#define EPB 4096          // edges per hist/part block
#define NPB 391           // ceil(NE/EPB)

typedef float f32x4 __attribute__((ext_vector_type(4)));
typedef float f32x2 __attribute__((ext_vector_type(2)));
typedef short s16x8 __attribute__((ext_vector_type(8)));

union Q16 { uint4 q; s16x8 v; };

// ---- ws layout (4-byte words) ----
#define OFS_BKT   0                     // bkt_cnt[512] | bkt_base[512] | bkt_cur[512] | dcnt[64] | dcur[64]
#define OFS_DEG   (8*NN)                // int[NN]
#define OFS_RP    (9*NN)                // int[NN]
#define OFS_BSUM  (10*NN)               // reused: bias2[128] fp32 (b2l + sh·w2r)
#define OFS_RANK  (10*NN + 1024)        // reused: perm[NN] uint2 {node|deg<<17, rp} -> 2*NN words
#define OFS_CSR   (OFS_RANK + NE/2)
#define OFS_INV   (OFS_CSR + NE)
#define OFS_HAS   (OFS_INV + NN)
#define OFS_XB    (OFS_HAS + NN)        // x bf16 [NN][64]   -> 32*NN words
#define OFS_XB8   (OFS_XB + 32*NN)      // x fp8 [NN][64]    -> 16*NN words
#define OFS_A1B   (OFS_XB8 + 16*NN)     // agg1 bf16 [NN][64]-> 32*NN
#define OFS_H1B   (OFS_A1B + 32*NN)     // h1 bf16 STANDARD cols [NN][128] -> 64*NN
#define OFS_H1F8  (OFS_H1B + 64*NN)     // h1 fp8 PERMUTED [NN][128] -> 32*NN
#define OFS_A2B   (OFS_H1F8 + 32*NN)    // BN'd agg2 bf16 PERMUTED [NN][128] -> 64*NN
                                        //   (also reused EARLY as packed-edge buffer, NE words)
#define OFS_W1T   (OFS_A2B + 64*NN)     // [128][128] ush -> 8192 words
#define OFS_W2T   (OFS_W1T + 8192)      // [128][256] ush (a2b-half K permuted; h1-half K STANDARD, sc-scaled by k_wfix) -> 16384
#define OFS_WFCT  (OFS_W2T + 16384)     // [16][128] ush (K standard) -> 1024 words
#define OFS_STATS (OFS_WFCT + 1024)     // 512: [sc 128][sh 128][sc' 128][sh' 128]
#define OFS_PART  (OFS_STATS + 512)     // 768*256

// col permutation: c' = l15*8 + nt  <->  c = nt*16 + l15  (P(c') = (c'&7)*16 + (c'>>3))
// stats[256+c'] = sc[P(c')], stats[384+c'] = sh[P(c')]
// NOTE (empirical, rounds 5-10): per-tile __syncthreads in the persistent MFMA loops
// are LOAD-BEARING FOR L2 LOCALITY — removing them desyncs waves and blows HBM
// traffic ~2.5x (FETCH 74->116MB signatures). Do not remove.

__device__ __forceinline__ unsigned short f2bf(float f) {
    unsigned u = __float_as_uint(f);
    return (unsigned short)((u + 0x7FFFu + ((u >> 16) & 1u)) >> 16);
}
__device__ __forceinline__ float bfl(unsigned u) { return __uint_as_float(u << 16); }
__device__ __forceinline__ float bfh(unsigned u) { return __uint_as_float(u & 0xFFFF0000u); }

// ---- fp8 e4m3 pack/unpack (HW cvt on gfx950; software fallback) ----
#if __has_builtin(__builtin_amdgcn_cvt_pk_f32_fp8) && __has_builtin(__builtin_amdgcn_cvt_pk_fp8_f32)
__device__ __forceinline__ f32x2 cvt2_lo(unsigned w) {
    return __builtin_amdgcn_cvt_pk_f32_fp8((int)w, false);
}
__device__ __forceinline__ f32x2 cvt2_hi(unsigned w) {
    return __builtin_amdgcn_cvt_pk_f32_fp8((int)w, true);
}
__device__ __forceinline__ unsigned pk_fp8x4(float a, float b, float c, float d) {
    int w = __builtin_amdgcn_cvt_pk_fp8_f32(a, b, 0, false);
    w = __builtin_amdgcn_cvt_pk_fp8_f32(c, d, w, true);
    return (unsigned)w;
}
#else
__device__ __forceinline__ float sw_fp82f(unsigned v) {
    unsigned s = (v & 0x80u) << 24;
    unsigned e = (v >> 3) & 15u, m = v & 7u;
    float r = (e == 0) ? ((float)m * 0.001953125f)
                       : __uint_as_float(((e + 120u) << 23) | (m << 20));
    return __uint_as_float(s | __float_as_uint(r));
}
__device__ __forceinline__ f32x2 cvt2_lo(unsigned w) {
    return (f32x2){sw_fp82f(w & 255u), sw_fp82f((w >> 8) & 255u)};
}
__device__ __forceinline__ f32x2 cvt2_hi(unsigned w) {
    return (f32x2){sw_fp82f((w >> 16) & 255u), sw_fp82f(w >> 24)};
}
__device__ __forceinline__ unsigned sw_f2fp8(float f) {
    unsigned b = __float_as_uint(f);
    unsigned s = (b >> 24) & 0x80u;
    float af = fabsf(f);
    if (af < 0.0009765625f) return s;
    if (af >= 448.f) return s | 0x7Eu;
    int e = (int)((b >> 23) & 255u) - 127;
    if (e < -6) {
        int q = (int)rintf(af * 512.f);
        return s | (unsigned)q;
    }
    unsigned man = b & 0x7FFFFFu;
    unsigned r = (man + 0x7FFFFu + ((man >> 20) & 1u)) >> 20;
    unsigned enc = ((unsigned)(e + 7) << 3) + r;
    if (enc >= 0x7Fu) enc = 0x7Eu;
    return s | enc;
}
__device__ __forceinline__ unsigned pk_fp8x4(float a, float b, float c, float d) {
    return sw_f2fp8(a) | (sw_f2fp8(b) << 8) | (sw_f2fp8(c) << 16) | (sw_f2fp8(d) << 24);
}
#endif

// ---------------- init: cast x -> bf16+fp8, weights -> transposed bf16 ----------------
#define CAST_BLOCKS 6250   // NN*16/256
#define PREP_BLOCKS 200    // (16384+32768+2048)/256
__global__ void k_init(const float4* __restrict__ x4, uint2* __restrict__ xb,
                       unsigned* __restrict__ xb8,
                       const float* __restrict__ w1l, const float* __restrict__ w1r,
                       const float* __restrict__ w2l, const float* __restrict__ w2r,
                       const float* __restrict__ wfc,
                       unsigned short* __restrict__ W1T, unsigned short* __restrict__ W2T,
                       unsigned short* __restrict__ wfcT) {
    int b = blockIdx.x, t = threadIdx.x;
    if (b < CAST_BLOCKS) {
        int i = b * 256 + t;
        float4 v = x4[i];
        uint2 o;
        o.x = (unsigned)f2bf(v.x) | ((unsigned)f2bf(v.y) << 16);
        o.y = (unsigned)f2bf(v.z) | ((unsigned)f2bf(v.w) << 16);
        xb[i] = o;
        xb8[i] = pk_fp8x4(v.x, v.y, v.z, v.w);
        return;
    }
    int u = (b - CAST_BLOCKS) * 256 + t;
    if (u < 16384) {
        int n = u >> 7, k = u & 127;
        float v = (k < 64) ? w1l[k * 128 + n] : w1r[(k - 64) * 128 + n];
        W1T[u] = f2bf(v);
    } else if (u < 16384 + 32768) {
        int u2 = u - 16384;
        int n = u2 >> 8, kk = u2 & 255;
        float v;
        if (kk < 128) {
            int pk = (kk & 7) * 16 + (kk >> 3);   // permuted lin_l K-row (matches a2b)
            v = w2l[pk * 128 + n];
        } else {
            v = w2r[(kk - 128) * 128 + n];        // STANDARD K (matches std h1b; k_wfix rescales)
        }
        W2T[u2] = f2bf(v);
    } else {
        int u3 = u - 16384 - 32768;
        int o = u3 >> 7, k = u3 & 127;
        wfcT[u3] = f2bf(wfc[k * 16 + o]);         // standard K (Asm holds std cols)
    }
}

// ---------------- CSR build: bucketed counting sort (no global per-edge atomics) ----
__global__ __launch_bounds__(256) void k_hist(const int* __restrict__ ei,
                                              int* __restrict__ bkt_cnt) {
    __shared__ int lc[NBK];
    int t = threadIdx.x;
    for (int i = t; i < NBK; i += 256) lc[i] = 0;
    __syncthreads();
    int e0 = blockIdx.x * EPB;
    int e1 = e0 + EPB; if (e1 > NE) e1 = NE;
    for (int e = e0 + t; e < e1; e += 256) {
        int d = ei[NE + e];
        atomicAdd(&lc[d >> 8], 1);
    }
    __syncthreads();
    for (int i = t; i < NBK; i += 256)
        if (lc[i]) atomicAdd(&bkt_cnt[i], lc[i]);
}

__global__ void k_bscan(const int* __restrict__ cnt, int* __restrict__ base,
                        int* __restrict__ cur) {
    __shared__ int s[512];
    int t = threadIdx.x;
    int v = (t < NBK) ? cnt[t] : 0;
    s[t] = v;
    __syncthreads();
    for (int o = 1; o < 512; o <<= 1) {
        int u = (t >= o) ? s[t - o] : 0;
        __syncthreads();
        s[t] += u;
        __syncthreads();
    }
    if (t < NBK) {
        int b = s[t] - v;
        base[t] = b;
        cur[t] = b;
        if (t == NBK - 1) base[NBK] = s[t];   // == NE
    }
}

__global__ __launch_bounds__(256) void k_part(const int* __restrict__ ei,
                                              int* __restrict__ bkt_cur,
                                              unsigned* __restrict__ packed) {
    __shared__ int lc[NBK];
    __shared__ int gb[NBK];
    int t = threadIdx.x;
    for (int i = t; i < NBK; i += 256) lc[i] = 0;
    __syncthreads();
    int e0 = blockIdx.x * EPB;
    int e1 = e0 + EPB; if (e1 > NE) e1 = NE;
    for (int e = e0 + t; e < e1; e += 256) {
        int d = ei[NE + e];
        atomicAdd(&lc[d >> 8], 1);
    }
    __syncthreads();
    for (int i = t; i < NBK; i += 256) {
        int c = lc[i];
        gb[i] = c ? atomicAdd(&bkt_cur[i], c) : 0;  // reserve per-(block,bucket) range
        lc[i] = 0;
    }
    __syncthreads();
    for (int e = e0 + t; e < e1; e += 256) {
        int d = ei[NE + e];
        int s = ei[e];
        int b = d >> 8;
        int r = atomicAdd(&lc[b], 1);               // local rank (LDS)
        packed[gb[b] + r] = (unsigned)s | ((unsigned)(d & 255) << 17);
    }
}

__global__ __launch_bounds__(256) void k_bucket(const unsigned* __restrict__ packed,
                                                const int* __restrict__ bkt_base,
                                                int* __restrict__ csr, int* __restrict__ deg,
                                                int* __restrict__ rp,
                                                int* __restrict__ dcnt) {
    __shared__ int cnt[256];
    __shared__ int off[256];
    __shared__ int dh[64];
    int b = blockIdx.x, t = threadIdx.x;
    int base = bkt_base[b], end = bkt_base[b + 1];
    cnt[t] = 0;
    if (t < 64) dh[t] = 0;
    __syncthreads();
    for (int i = base + t; i < end; i += 256) {
        unsigned u = packed[i];
        atomicAdd(&cnt[u >> 17], 1);
    }
    __syncthreads();
    int v = cnt[t];
    int node = b * 256 + t;
    if (node < NN) atomicAdd(&dh[v < 63 ? v : 63], 1);
    off[t] = v;
    __syncthreads();
    for (int o = 1; o < 256; o <<= 1) {
        int u = (t >= o) ? off[t - o] : 0;
        __syncthreads();
        off[t] += u;
        __syncthreads();
    }
    int excl = off[t] - v;                 // exclusive prefix within bucket
    if (node < NN) {
        deg[node] = v;
        rp[node] = base + excl;
    }
    cnt[t] = base + excl;                  // reuse as scatter cursor
    __syncthreads();
    for (int i = base + t; i < end; i += 256) {
        unsigned u = packed[i];
        int p = atomicAdd(&cnt[u >> 17], 1);
        csr[p] = (int)(u & 0x1FFFFu);
    }
    if (t < 64 && dh[t]) atomicAdd(&dcnt[t], dh[t]);
}

__global__ void k_dscan(const int* __restrict__ dcnt, int* __restrict__ dcur) {
    __shared__ int s[64];
    int t = threadIdx.x;
    int v = dcnt[t];
    s[t] = v;
    __syncthreads();
    for (int o = 1; o < 64; o <<= 1) {
        int u = (t >= o) ? s[t - o] : 0;
        __syncthreads();
        s[t] += u;
        __syncthreads();
    }
    dcur[t] = s[t] - v;
}

__global__ __launch_bounds__(256) void k_dperm(const int* __restrict__ deg,
                                               const int* __restrict__ rp,
                                               int* __restrict__ dcur,
                                               uint2* __restrict__ perm) {
    __shared__ int lc[64];
    __shared__ int gb[64];
    int t = threadIdx.x;
    if (t < 64) lc[t] = 0;
    __syncthreads();
    int node = blockIdx.x * 256 + t;
    int bin = 0, r = 0, d = 0;
    bool ok = node < NN;
    if (ok) {
        d = deg[node];
        bin = d < 63 ? d : 63;
        r = atomicAdd(&lc[bin], 1);
    }
    __syncthreads();
    if (t < 64) gb[t] = lc[t] ? atomicAdd(&dcur[t], lc[t]) : 0;
    __syncthreads();
    if (ok) perm[gb[bin] + r] = make_uint2((unsigned)node | ((unsigned)d << 17),
                                           (unsigned)rp[node]);
}

// ---------------- gather layer 1 (fp8): agg1b[n] = bf16(mean x[s]) ----------------
__global__ __launch_bounds__(256) void k_agg1(
    const uint4* __restrict__ xb8, const int* __restrict__ csr,
    const uint2* __restrict__ perm, uint4* __restrict__ agg1b) {
    int t = threadIdx.x;
    int lane = t & 63;
    int grp = lane >> 2, f = lane & 3;
    int slot = blockIdx.x * 64 + (t >> 6) * 16 + grp;
    bool ok = slot < NN;
    uint2 pn = ok ? perm[slot] : make_uint2(0u, 0u);
    int node = (int)(pn.x & NMSK);
    int len = ok ? (int)(pn.x >> 17) : 0;
    const int* cp = csr + pn.y;
    f32x2 c[8];
#pragma unroll
    for (int k = 0; k < 8; k++) c[k] = (f32x2){0.f, 0.f};
    int s0 = cp[0] & NMSK, s1 = cp[1] & NMSK, s2 = cp[2] & NMSK, s3 = cp[3] & NMSK;
    int j = 0;
    while (j + 3 < len) {
        int n0 = cp[j + 4] & NMSK, n1 = cp[j + 5] & NMSK;
        int n2 = cp[j + 6] & NMSK, n3 = cp[j + 7] & NMSK;
        uint4 u0 = xb8[s0 * 4 + f];
        uint4 u1 = xb8[s1 * 4 + f];
        uint4 u2 = xb8[s2 * 4 + f];
        uint4 u3 = xb8[s3 * 4 + f];
        c[0] += cvt2_lo(u0.x); c[1] += cvt2_hi(u0.x); c[2] += cvt2_lo(u0.y); c[3] += cvt2_hi(u0.y);
        c[4] += cvt2_lo(u0.z); c[5] += cvt2_hi(u0.z); c[6] += cvt2_lo(u0.w); c[7] += cvt2_hi(u0.w);
        c[0] += cvt2_lo(u1.x); c[1] += cvt2_hi(u1.x); c[2] += cvt2_lo(u1.y); c[3] += cvt2_hi(u1.y);
        c[4] += cvt2_lo(u1.z); c[5] += cvt2_hi(u1.z); c[6] += cvt2_lo(u1.w); c[7] += cvt2_hi(u1.w);
        c[0] += cvt2_lo(u2.x); c[1] += cvt2_hi(u2.x); c[2] += cvt2_lo(u2.y); c[3] += cvt2_hi(u2.y);
        c[4] += cvt2_lo(u2.z); c[5] += cvt2_hi(u2.z); c[6] += cvt2_lo(u2.w); c[7] += cvt2_hi(u2.w);
        c[0] += cvt2_lo(u3.x); c[1] += cvt2_hi(u3.x); c[2] += cvt2_lo(u3.y); c[3] += cvt2_hi(u3.y);
        c[4] += cvt2_lo(u3.z); c[5] += cvt2_hi(u3.z); c[6] += cvt2_lo(u3.w); c[7] += cvt2_hi(u3.w);
        j += 4; s0 = n0; s1 = n1; s2 = n2; s3 = n3;
    }
    while (j < len) {
        uint4 u = xb8[s0 * 4 + f];
        c[0] += cvt2_lo(u.x); c[1] += cvt2_hi(u.x); c[2] += cvt2_lo(u.y); c[3] += cvt2_hi(u.y);
        c[4] += cvt2_lo(u.z); c[5] += cvt2_hi(u.z); c[6] += cvt2_lo(u.w); c[7] += cvt2_hi(u.w);
        s0 = s1; s1 = s2; s2 = s3; ++j;
    }
    float ic = 1.0f / fmaxf((float)len, 1.0f);
    uint4 o0, o1;
    o0.x = (unsigned)f2bf(c[0][0] * ic) | ((unsigned)f2bf(c[0][1] * ic) << 16);
    o0.y = (unsigned)f2bf(c[1][0] * ic) | ((unsigned)f2bf(c[1][1] * ic) << 16);
    o0.z = (unsigned)f2bf(c[2][0] * ic) | ((unsigned)f2bf(c[2][1] * ic) << 16);
    o0.w = (unsigned)f2bf(c[3][0] * ic) | ((unsigned)f2bf(c[3][1] * ic) << 16);
    o1.x = (unsigned)f2bf(c[4][0] * ic) | ((unsigned)f2bf(c[4][1] * ic) << 16);
    o1.y = (unsigned)f2bf(c[5][0] * ic) | ((unsigned)f2bf(c[5][1] * ic) << 16);
    o1.z = (unsigned)f2bf(c[6][0] * ic) | ((unsigned)f2bf(c[6][1] * ic) << 16);
    o1.w = (unsigned)f2bf(c[7][0] * ic) | ((unsigned)f2bf(c[7][1] * ic) << 16);
    if (ok) {
        agg1b[node * 8 + f * 2] = o0;
        agg1b[node * 8 + f * 2 + 1] = o1;
    }
}

// ---------------- gather layer 2 (fp8, permuted cols) + BN fold ----------------
__global__ __launch_bounds__(256) void k_agg2(
    const uint4* __restrict__ h1f8, const int* __restrict__ csr,
    const float* __restrict__ statsp, const uint2* __restrict__ perm,
    uint4* __restrict__ a2b) {
    int t = threadIdx.x;
    int lane = t & 63;
    int grp = lane >> 3, f = lane & 7;
    int slot = blockIdx.x * 32 + (t >> 6) * 8 + grp;   // NN % 32 == 0
    uint2 pn = perm[slot];
    int node = (int)(pn.x & NMSK);
    int len = (int)(pn.x >> 17);
    const int* cp = csr + pn.y;
    f32x2 c[8];
#pragma unroll
    for (int k = 0; k < 8; k++) c[k] = (f32x2){0.f, 0.f};
    int s0 = cp[0] & NMSK, s1 = cp[1] & NMSK, s2 = cp[2] & NMSK, s3 = cp[3] & NMSK;
    int j = 0;
    while (j + 3 < len) {
        int n0 = cp[j + 4] & NMSK, n1 = cp[j + 5] & NMSK;
        int n2 = cp[j + 6] & NMSK, n3 = cp[j + 7] & NMSK;
        uint4 u0 = h1f8[s0 * 8 + f];
        uint4 u1 = h1f8[s1 * 8 + f];
        uint4 u2 = h1f8[s2 * 8 + f];
        uint4 u3 = h1f8[s3 * 8 + f];
        c[0] += cvt2_lo(u0.x); c[1] += cvt2_hi(u0.x); c[2] += cvt2_lo(u0.y); c[3] += cvt2_hi(u0.y);
        c[4] += cvt2_lo(u0.z); c[5] += cvt2_hi(u0.z); c[6] += cvt2_lo(u0.w); c[7] += cvt2_hi(u0.w);
        c[0] += cvt2_lo(u1.x); c[1] += cvt2_hi(u1.x); c[2] += cvt2_lo(u1.y); c[3] += cvt2_hi(u1.y);
        c[4] += cvt2_lo(u1.z); c[5] += cvt2_hi(u1.z); c[6] += cvt2_lo(u1.w); c[7] += cvt2_hi(u1.w);
        c[0] += cvt2_lo(u2.x); c[1] += cvt2_hi(u2.x); c[2] += cvt2_lo(u2.y); c[3] += cvt2_hi(u2.y);
        c[4] += cvt2_lo(u2.z); c[5] += cvt2_hi(u2.z); c[6] += cvt2_lo(u2.w); c[7] += cvt2_hi(u2.w);
        c[0] += cvt2_lo(u3.x); c[1] += cvt2_hi(u3.x); c[2] += cvt2_lo(u3.y); c[3] += cvt2_hi(u3.y);
        c[4] += cvt2_lo(u3.z); c[5] += cvt2_hi(u3.z); c[6] += cvt2_lo(u3.w); c[7] += cvt2_hi(u3.w);
        j += 4; s0 = n0; s1 = n1; s2 = n2; s3 = n3;
    }
    while (j < len) {
        uint4 u = h1f8[s0 * 8 + f];
        c[0] += cvt2_lo(u.x); c[1] += cvt2_hi(u.x); c[2] += cvt2_lo(u.y); c[3] += cvt2_hi(u.y);
        c[4] += cvt2_lo(u.z); c[5] += cvt2_hi(u.z); c[6] += cvt2_lo(u.w); c[7] += cvt2_hi(u.w);
        s0 = s1; s1 = s2; s2 = s3; ++j;
    }
    float ic = 1.0f / fmaxf((float)len, 1.0f);
    float hv = (len > 0) ? 1.0f : 0.0f;
    const float4* sc4 = (const float4*)statsp;
    const float4* sh4 = (const float4*)(statsp + 128);
    float v[16];
#pragma unroll
    for (int q = 0; q < 4; q++) {
        float4 sc = sc4[f * 4 + q];
        float4 sh = sh4[f * 4 + q];
        v[q * 4 + 0] = c[q * 2][0] * ic * sc.x + sh.x * hv;
        v[q * 4 + 1] = c[q * 2][1] * ic * sc.y + sh.y * hv;
        v[q * 4 + 2] = c[q * 2 + 1][0] * ic * sc.z + sh.z * hv;
        v[q * 4 + 3] = c[q * 2 + 1][1] * ic * sc.w + sh.w * hv;
    }
    uint4 o0, o1;
    o0.x = (unsigned)f2bf(v[0]) | ((unsigned)f2bf(v[1]) << 16);
    o0.y = (unsigned)f2bf(v[2]) | ((unsigned)f2bf(v[3]) << 16);
    o0.z = (unsigned)f2bf(v[4]) | ((unsigned)f2bf(v[5]) << 16);
    o0.w = (unsigned)f2bf(v[6]) | ((unsigned)f2bf(v[7]) << 16);
    o1.x = (unsigned)f2bf(v[8]) | ((unsigned)f2bf(v[9]) << 16);
    o1.y = (unsigned)f2bf(v[10]) | ((unsigned)f2bf(v[11]) << 16);
    o1.z = (unsigned)f2bf(v[12]) | ((unsigned)f2bf(v[13]) << 16);
    o1.w = (unsigned)f2bf(v[14]) | ((unsigned)f2bf(v[15]) << 16);
    a2b[node * 16 + f * 2] = o0;
    a2b[node * 16 + f * 2 + 1] = o1;
}

// ---------------- layer 1 MFMA (round-8 proven form + next-tile A prefetch) ----
// A direct global->VGPR; W staged once; h1b STANDARD via Asm readback (barriers kept);
// next tile's af loaded right after MFMA (af dead there) -> latency hides under
// epilogue + 2 barriers + readback.
__global__ __launch_bounds__(256, 3) void k_gemm1(
    const uint4* __restrict__ agg1b, const uint4* __restrict__ xb,
    const uint4* __restrict__ W1T, const float* __restrict__ b1l,
    uint4* __restrict__ h1b, uint2* __restrict__ h1f8, float* __restrict__ part) {
    __shared__ unsigned short Wsm[128 * LDA];  // 34816 B
    __shared__ unsigned short Asm[64 * LDA];   // 17408 B
    __shared__ float cs[128], cq[128];
    const int t = threadIdx.x;
    const int w = t >> 6, lane = t & 63, quad = lane >> 4, l15 = lane & 15;
    if (t < 128) { cs[t] = 0.f; cq[t] = 0.f; }
    {   // stage W1T once (row=256B=16 uint4)
        int r = t >> 1, h = t & 1;
#pragma unroll
        for (int i = 0; i < 8; i++) {
            uint4 v = W1T[r * 16 + h * 8 + i];
            *(uint4*)&Wsm[r * LDA + h * 64 + i * 8] = v;
        }
    }
    float bias[8];
#pragma unroll
    for (int nt = 0; nt < 8; nt++) bias[nt] = b1l[nt * 16 + l15];
    float colsum[8] = {0, 0, 0, 0, 0, 0, 0, 0};
    float colsq[8]  = {0, 0, 0, 0, 0, 0, 0, 0};
    const int arow = 16 * w + l15;          // this lane's A-fragment row
    __syncthreads();                        // W staged, cs/cq init

    // initial A-fragment load for first tile
    Q16 af[4];
    {
        const int base0 = blockIdx.x * 64;
        const int valid0 = (NN - base0 < 64) ? (NN - base0) : 64;
        const int gm0 = base0 + arow;
        const bool ok0 = arow < valid0;
#pragma unroll
        for (int kc = 0; kc < 2; kc++)
            af[kc].q = ok0 ? agg1b[gm0 * 8 + kc * 4 + quad] : make_uint4(0, 0, 0, 0);
#pragma unroll
        for (int kc = 0; kc < 2; kc++)
            af[2 + kc].q = ok0 ? xb[gm0 * 8 + kc * 4 + quad] : make_uint4(0, 0, 0, 0);
    }

    for (int g = blockIdx.x; g < NT1; g += gridDim.x) {
        const int base = g * 64;
        const int valid = (NN - base < 64) ? (NN - base) : 64;
        f32x4 acc[8];
#pragma unroll
        for (int nt = 0; nt < 8; nt++) acc[nt] = (f32x4){bias[nt], bias[nt], bias[nt], bias[nt]};
#pragma unroll
        for (int kc = 0; kc < 4; kc++) {
#pragma unroll
            for (int nt = 0; nt < 8; nt++) {
                s16x8 bf = *(const s16x8*)&Wsm[(nt * 16 + l15) * LDA + kc * 32 + quad * 8];
                acc[nt] = __builtin_amdgcn_mfma_f32_16x16x32_bf16(af[kc].v, bf, acc[nt], 0, 0, 0);
            }
        }
        {   // prefetch next tile's A-fragments (af dead after MFMA)
            const int gn = g + gridDim.x;
            const bool okg = gn < NT1;
            const int basen = okg ? gn * 64 : 0;
            const int validn = (NN - basen < 64) ? (NN - basen) : 64;
            const int gmn = basen + arow;
            const bool okn = okg && (arow < validn);
#pragma unroll
            for (int kc = 0; kc < 2; kc++)
                af[kc].q = okn ? agg1b[gmn * 8 + kc * 4 + quad] : make_uint4(0, 0, 0, 0);
#pragma unroll
            for (int kc = 0; kc < 2; kc++)
                af[2 + kc].q = okn ? xb[gmn * 8 + kc * 4 + quad] : make_uint4(0, 0, 0, 0);
        }
        // epilogue: norm+relu+stats; bf16 into Asm (std cols); fp8 direct (permuted)
        float ssr[4] = {0, 0, 0, 0};
#pragma unroll
        for (int nt = 0; nt < 8; nt++)
#pragma unroll
            for (int r = 0; r < 4; r++) ssr[r] += acc[nt][r] * acc[nt][r];
#pragma unroll
        for (int r = 0; r < 4; r++) {
            ssr[r] += __shfl_xor(ssr[r], 1); ssr[r] += __shfl_xor(ssr[r], 2);
            ssr[r] += __shfl_xor(ssr[r], 4); ssr[r] += __shfl_xor(ssr[r], 8);
        }
#pragma unroll
        for (int r = 0; r < 4; r++) {
            int mrow = 16 * w + quad * 4 + r;
            float iv = 1.0f / fmaxf(sqrtf(ssr[r]), 1e-12f);
            bool okr = mrow < valid;
            float v[8];
#pragma unroll
            for (int nt = 0; nt < 8; nt++) {
                float vv = fmaxf(acc[nt][r] * iv, 0.f);
                if (!okr) vv = 0.f;
                v[nt] = vv;
                colsum[nt] += vv;
                colsq[nt] += vv * vv;
                Asm[mrow * LDA + nt * 16 + l15] = f2bf(vv);
            }
            if (okr) {
                uint2 o;
                o.x = pk_fp8x4(v[0], v[1], v[2], v[3]);
                o.y = pk_fp8x4(v[4], v[5], v[6], v[7]);
                h1f8[(base + mrow) * 16 + l15] = o;   // permuted col' = l15*8+nt
            }
        }
        __syncthreads();
        {   // coalesced h1b store (row=256B=16 uint4), STANDARD layout
            int m = t >> 2, p = t & 3;
            if (m < valid) {
                int gm2 = base + m;
#pragma unroll
                for (int i = 0; i < 4; i++) {
                    uint4 v = *(const uint4*)&Asm[m * LDA + p * 32 + i * 8];
                    h1b[gm2 * 16 + p * 4 + i] = v;
                }
            }
        }
        __syncthreads();  // readback done before next epilogue overwrites Asm
    }
    __syncthreads();
#pragma unroll
    for (int nt = 0; nt < 8; nt++) {
        atomicAdd(&cs[nt * 16 + l15], colsum[nt]);
        atomicAdd(&cq[nt * 16 + l15], colsq[nt]);
    }
    __syncthreads();
    if (t < 128) {
        part[blockIdx.x * 256 + t] = cs[t];
        part[blockIdx.x * 256 + 128 + t] = cq[t];
    }
}

// ---------------- BN finalize: stats + permuted copy ----------------
__global__ void k_bnfin(const float* __restrict__ part, const float* __restrict__ gamma,
                        const float* __restrict__ beta, float* __restrict__ stats) {
    int t = threadIdx.x;  // 128 (channel)
    float s = 0.f, q = 0.f;
    for (int b = 0; b < PART_BLOCKS; b++) {
        s += part[b * 256 + t];
        q += part[b * 256 + 128 + t];
    }
    float mean = s / (float)NN;
    float var = q / (float)NN - mean * mean;
    float sc = gamma[t] * rsqrtf(var + 1e-5f);
    float sh = beta[t] - mean * sc;
    stats[t] = sc;
    stats[128 + t] = sh;
    int cp = (t & 15) * 8 + (t >> 4);   // permuted position of channel t
    stats[256 + cp] = sc;
    stats[384 + cp] = sh;
}

// ---------------- W2 fixup: fold BN scale into lin_r weights, shift into bias ----
// (sc*h1+sh) @ w2r == h1 @ (diag(sc)·w2r) + sh·w2r.  STANDARD K positions.
__global__ void k_wfix(const float* __restrict__ w2r, const float* __restrict__ stats,
                       const float* __restrict__ b2l,
                       unsigned short* __restrict__ W2T, float* __restrict__ bias2) {
    __shared__ float sb[128];
    int n = blockIdx.x;       // 128 (output channel)
    int k = threadIdx.x;      // 128 (std K position = h1 channel)
    float wv = w2r[k * 128 + n];
    W2T[n * 256 + 128 + k] = f2bf(wv * stats[k]);
    sb[k] = stats[128 + k] * wv;                    // sh[k] * w2r[k][n]
    __syncthreads();
    for (int o = 64; o > 0; o >>= 1) {
        if (k < o) sb[k] += sb[k + o];
        __syncthreads();
    }
    if (k == 0) bias2[n] = b2l[n] + sb[0];
}

// ---------------- layer 2 MFMA (K=256) + L2norm + FC (round-8 form + prefetch) ----
// Persistent 512-thread blocks (grid 256); FULL BN-prefolded W2T in LDS (staged once);
// A-fragments raw direct global->VGPR; FC via Asm redistribution (barriers kept);
// next tile's af loaded right after MFMA.
__global__ __launch_bounds__(512) void k_gemm2(
    const uint4* __restrict__ a2b, const uint4* __restrict__ h1b,
    const uint4* __restrict__ W2T, const float* __restrict__ bias2,
    const uint4* __restrict__ wfcT, const float* __restrict__ bfc,
    float* __restrict__ out) {
    __shared__ unsigned short WsmF[128 * LDW];   // 67584 B (full W2T [N=128][K=256])
    __shared__ unsigned short Asm[128 * LDA];    // 34816 B (h2 for FC redistribution)
    __shared__ unsigned short wfcsm[16 * LDA];   // 4352 B
    const int t = threadIdx.x;
    const int w = t >> 6, lane = t & 63, quad = lane >> 4, l15 = lane & 15;

    {   // full W2T: row r (N), 512B = 32 uint4
        int r = t >> 2, seg = t & 3;
#pragma unroll
        for (int i = 0; i < 8; i++) {
            uint4 v = W2T[r * 32 + seg * 8 + i];
            *(uint4*)&WsmF[r * LDW + (seg * 8 + i) * 8] = v;
        }
    }
    if (t < 64) {   // wfcT: 16 rows x 256B
        int n = t >> 2, p = t & 3;
#pragma unroll
        for (int i = 0; i < 4; i++) {
            uint4 v = wfcT[n * 16 + p * 4 + i];
            *(uint4*)&wfcsm[n * LDA + p * 32 + i * 8] = v;
        }
    }
    float bias[8];
#pragma unroll
    for (int nt = 0; nt < 8; nt++) bias[nt] = bias2[nt * 16 + l15];
    const float fb = bfc[l15];
    const int arow = 16 * w + l15;          // 0..127
    __syncthreads();

    // initial A-fragment load for first tile
    Q16 af[8];
    {
        const int base0 = blockIdx.x * 128;
        const int valid0 = (NN - base0 < 128) ? (NN - base0) : 128;
        const int gm0 = base0 + arow;
        const bool ok0 = arow < valid0;
#pragma unroll
        for (int kc = 0; kc < 4; kc++)
            af[kc].q = ok0 ? a2b[gm0 * 16 + kc * 4 + quad] : make_uint4(0, 0, 0, 0);
#pragma unroll
        for (int kc = 0; kc < 4; kc++)
            af[4 + kc].q = ok0 ? h1b[gm0 * 16 + kc * 4 + quad] : make_uint4(0, 0, 0, 0);
    }

    for (int g = blockIdx.x; g < NT2; g += gridDim.x) {
        const int base = g * 128;
        const int valid = (NN - base < 128) ? (NN - base) : 128;

        f32x4 acc[8];
#pragma unroll
        for (int nt = 0; nt < 8; nt++) acc[nt] = (f32x4){bias[nt], bias[nt], bias[nt], bias[nt]};
#pragma unroll
        for (int kc = 0; kc < 8; kc++) {
#pragma unroll
            for (int nt = 0; nt < 8; nt++) {
                s16x8 bf = *(const s16x8*)&WsmF[(nt * 16 + l15) * LDW + kc * 32 + quad * 8];
                acc[nt] = __builtin_amdgcn_mfma_f32_16x16x32_bf16(af[kc].v, bf, acc[nt], 0, 0, 0);
            }
        }
        {   // prefetch next tile's A-fragments (af dead after MFMA)
            const int gn = g + gridDim.x;
            const bool okg = gn < NT2;
            const int basen = okg ? gn * 128 : 0;
            const int validn = (NN - basen < 128) ? (NN - basen) : 128;
            const int gmn = basen + arow;
            const bool okn = okg && (arow < validn);
#pragma unroll
            for (int kc = 0; kc < 4; kc++)
                af[kc].q = okn ? a2b[gmn * 16 + kc * 4 + quad] : make_uint4(0, 0, 0, 0);
#pragma unroll
            for (int kc = 0; kc < 4; kc++)
                af[4 + kc].q = okn ? h1b[gmn * 16 + kc * 4 + quad] : make_uint4(0, 0, 0, 0);
        }

        // epilogue: L2 norm, h2 -> Asm (standard col positions)
        float ssr[4] = {0, 0, 0, 0};
#pragma unroll
        for (int nt = 0; nt < 8; nt++)
#pragma unroll
            for (int r = 0; r < 4; r++) ssr[r] += acc[nt][r] * acc[nt][r];
#pragma unroll
        for (int r = 0; r < 4; r++) {
            ssr[r] += __shfl_xor(ssr[r], 1); ssr[r] += __shfl_xor(ssr[r], 2);
            ssr[r] += __shfl_xor(ssr[r], 4); ssr[r] += __shfl_xor(ssr[r], 8);
        }
#pragma unroll
        for (int r = 0; r < 4; r++) {
            int mrow = 16 * w + quad * 4 + r;
            float iv = 1.0f / fmaxf(sqrtf(ssr[r]), 1e-12f);
#pragma unroll
            for (int nt = 0; nt < 8; nt++) {
                Asm[mrow * LDA + nt * 16 + l15] = f2bf(acc[nt][r] * iv);
            }
        }
        __syncthreads();   // h2 complete
        // FC: 16x16 tile per wave, K=128
        f32x4 a2 = (f32x4){fb, fb, fb, fb};
#pragma unroll
        for (int kc = 0; kc < 4; kc++) {
            s16x8 af2 = *(const s16x8*)&Asm[arow * LDA + kc * 32 + quad * 8];
            s16x8 bf2 = *(const s16x8*)&wfcsm[l15 * LDA + kc * 32 + quad * 8];
            a2 = __builtin_amdgcn_mfma_f32_16x16x32_bf16(af2, bf2, a2, 0, 0, 0);
        }
#pragma unroll
        for (int r = 0; r < 4; r++) {
            int mrow = 16 * w + quad * 4 + r;
            if (mrow < valid) out[(base + mrow) * 16 + l15] = a2[r];
        }
        __syncthreads();   // FC reads done before next tile overwrites Asm
    }
}

extern "C" void kernel_launch(void* const* d_in, const int* in_sizes, int n_in,
                              void* d_out, int out_size, void* d_ws, size_t ws_size,
                              hipStream_t stream) {
    const float* x     = (const float*)d_in[0];
    const int*   ei    = (const int*)d_in[1];
    const float* w1l   = (const float*)d_in[2];
    const float* b1l   = (const float*)d_in[3];
    const float* w1r   = (const float*)d_in[4];
    const float* gamma = (const float*)d_in[5];
    const float* beta  = (const float*)d_in[6];
    const float* w2l   = (const float*)d_in[7];
    const float* b2l   = (const float*)d_in[8];
    const float* w2r   = (const float*)d_in[9];
    const float* wfc   = (const float*)d_in[10];
    const float* bfc   = (const float*)d_in[11];
    float* out = (float*)d_out;

    float* W = (float*)d_ws;
    int* bkt_cnt  = (int*)(W + OFS_BKT);          // [512]
    int* bkt_base = bkt_cnt + 512;                // [512] (uses index NBK)
    int* bkt_cur  = bkt_cnt + 1024;               // [512]
    int* dcnt     = bkt_cnt + 1536;               // [64]
    int* dcur     = bkt_cnt + 1600;               // [64]
    int* deg   = (int*)(W + OFS_DEG);
    int* rp    = (int*)(W + OFS_RP);
    float* bias2 = W + OFS_BSUM;                  // [128] fp32
    uint2* perm = (uint2*)(W + OFS_RANK);         // 2*NN words (fat records)
    int* csr   = (int*)(W + OFS_CSR);
    unsigned* xb   = (unsigned*)(W + OFS_XB);
    unsigned* xb8  = (unsigned*)(W + OFS_XB8);
    unsigned* a1b  = (unsigned*)(W + OFS_A1B);
    unsigned* h1b  = (unsigned*)(W + OFS_H1B);
    unsigned* h1f8 = (unsigned*)(W + OFS_H1F8);
    unsigned* a2b  = (unsigned*)(W + OFS_A2B);
    unsigned* packed = (unsigned*)(W + OFS_A2B);  // NE words; dead before k_agg2 writes a2b
    unsigned short* W1T  = (unsigned short*)(W + OFS_W1T);
    unsigned short* W2T  = (unsigned short*)(W + OFS_W2T);
    unsigned short* wfcT = (unsigned short*)(W + OFS_WFCT);
    float* stats = W + OFS_STATS;          // [sc|sh|sc'|sh'] (512)
    float* part  = W + OFS_PART;

    hipMemsetAsync(bkt_cnt, 0, 1664 * sizeof(int), stream);

    k_init<<<CAST_BLOCKS + PREP_BLOCKS, 256, 0, stream>>>(
        (const float4*)x, (uint2*)xb, xb8, w1l, w1r, w2l, w2r, wfc, W1T, W2T, wfcT);
    k_hist  <<<NPB, 256, 0, stream>>>(ei, bkt_cnt);
    k_bscan <<<1, 512, 0, stream>>>(bkt_cnt, bkt_base, bkt_cur);
    k_part  <<<NPB, 256, 0, stream>>>(ei, bkt_cur, packed);
    k_bucket<<<NBK, 256, 0, stream>>>(packed, bkt_base, csr, deg, rp, dcnt);
    k_dscan <<<1, 64, 0, stream>>>(dcnt, dcur);
    k_dperm <<<NBK, 256, 0, stream>>>(deg, rp, dcur, perm);

    k_agg1 <<<(NN + 63) / 64, 256, 0, stream>>>((const uint4*)xb8, csr, perm, (uint4*)a1b);
    k_gemm1<<<PART_BLOCKS, 256, 0, stream>>>((const uint4*)a1b, (const uint4*)xb,
                                             (const uint4*)W1T, b1l, (uint4*)h1b,
                                             (uint2*)h1f8, part);
    k_bnfin<<<1, 128, 0, stream>>>(part, gamma, beta, stats);
    k_wfix <<<128, 128, 0, stream>>>(w2r, stats, b2l, W2T, bias2);
    k_agg2 <<<NN / 32, 256, 0, stream>>>((const uint4*)h1f8, csr, stats + 256, perm,
                                         (uint4*)a2b);
    k_gemm2<<<256, 512, 0, stream>>>((const uint4*)a2b, (const uint4*)h1b,
                                     (const uint4*)W2T, bias2, (const uint4*)wfcT,
                                     bfc, out);
}

// Round 12
// 293.577 us; speedup vs baseline: 1.2712x; 1.0471x over previous
//
#include <hip/hip_runtime.h>
#include <math.h>

#define NN 100000
#define NE 1600000
#define PART_BLOCKS 768
#define NT1 1563          // ceil(NN/64)  M-tiles (gemm1)
#define NT2 782           // ceil(NN/128) M-tiles (gemm2)
#define LDA 136           // padded LDS row stride (ushorts): 272 B, 16B-aligned
#define LDW 264           // padded W2T-full row stride (ushorts): 528 B
#define NMSK 0x1FFFF      // node-index mask (NN < 2^17); bounds derived addrs into ws

// ---- bucketed CSR build params ----
#define NBK 391           // ceil(NN/256) buckets of 256 dst nodes
#define EPB 4096          // edges per part block
#define NPB 391           // ceil(NE/EPB)
#define CAP 4600          // fixed bucket capacity: mean 4092, sd 64 -> mean+7.9sd.
                          // 391*4600=1,798,600 words fits csr region (NE+2*NN=1.8M).

typedef float f32x4 __attribute__((ext_vector_type(4)));
typedef float f32x2 __attribute__((ext_vector_type(2)));
typedef short s16x8 __attribute__((ext_vector_type(8)));

union Q16 { uint4 q; s16x8 v; };

// ---- ws layout (4-byte words) ----
#define OFS_BKT   0                     // (unused)[512] | (unused)[512] | bkt_cur[512] | dcnt[64] | dcur[64]
#define OFS_DEG   (8*NN)                // int[NN]
#define OFS_RP    (9*NN)                // int[NN]
#define OFS_BSUM  (10*NN)               // reused: bias2[128] fp32 (b2l + sh·w2r)
#define OFS_RANK  (10*NN + 1024)        // reused: perm[NN] uint2 {node|deg<<17, rp} -> 2*NN words
#define OFS_CSR   (OFS_RANK + NE/2)     // capacity-layout csr: NBK*CAP words (extends into dead INV/HAS)
#define OFS_INV   (OFS_CSR + NE)        // dead (absorbed by csr capacity layout)
#define OFS_HAS   (OFS_INV + NN)        // dead (absorbed by csr capacity layout)
#define OFS_XB    (OFS_HAS + NN)        // x bf16 [NN][64]   -> 32*NN words
#define OFS_XB8   (OFS_XB + 32*NN)      // x fp8 [NN][64]    -> 16*NN words
#define OFS_A1B   (OFS_XB8 + 16*NN)     // agg1 bf16 [NN][64]-> 32*NN
#define OFS_H1B   (OFS_A1B + 32*NN)     // h1 bf16 STANDARD cols [NN][128] -> 64*NN
#define OFS_H1F8  (OFS_H1B + 64*NN)     // h1 fp8 PERMUTED [NN][128] -> 32*NN
#define OFS_A2B   (OFS_H1F8 + 32*NN)    // BN'd agg2 bf16 PERMUTED [NN][128] -> 64*NN
                                        //   (also reused EARLY as packed-edge buffer, NBK*CAP words)
#define OFS_W1T   (OFS_A2B + 64*NN)     // [128][128] ush -> 8192 words
#define OFS_W2T   (OFS_W1T + 8192)      // [128][256] ush (a2b-half K permuted; h1-half K STANDARD, sc-scaled by k_wfix) -> 16384
#define OFS_WFCT  (OFS_W2T + 16384)     // [16][128] ush (K standard) -> 1024 words
#define OFS_STATS (OFS_WFCT + 1024)     // 512: [sc 128][sh 128][sc' 128][sh' 128]
#define OFS_PART  (OFS_STATS + 512)     // 768*256

// col permutation: c' = l15*8 + nt  <->  c = nt*16 + l15  (P(c') = (c'&7)*16 + (c'>>3))
// stats[256+c'] = sc[P(c')], stats[384+c'] = sh[P(c')]
// NOTE (empirical, rounds 5-10): per-tile __syncthreads in the persistent MFMA loops
// are LOAD-BEARING FOR L2 LOCALITY — removing them desyncs waves and blows HBM
// traffic ~2.5x (FETCH 74->116MB signatures). Do not remove.

__device__ __forceinline__ unsigned short f2bf(float f) {
    unsigned u = __float_as_uint(f);
    return (unsigned short)((u + 0x7FFFu + ((u >> 16) & 1u)) >> 16);
}
__device__ __forceinline__ float bfl(unsigned u) { return __uint_as_float(u << 16); }
__device__ __forceinline__ float bfh(unsigned u) { return __uint_as_float(u & 0xFFFF0000u); }

// ---- fp8 e4m3 pack/unpack (HW cvt on gfx950; software fallback) ----
#if __has_builtin(__builtin_amdgcn_cvt_pk_f32_fp8) && __has_builtin(__builtin_amdgcn_cvt_pk_fp8_f32)
__device__ __forceinline__ f32x2 cvt2_lo(unsigned w) {
    return __builtin_amdgcn_cvt_pk_f32_fp8((int)w, false);
}
__device__ __forceinline__ f32x2 cvt2_hi(unsigned w) {
    return __builtin_amdgcn_cvt_pk_f32_fp8((int)w, true);
}
__device__ __forceinline__ unsigned pk_fp8x4(float a, float b, float c, float d) {
    int w = __builtin_amdgcn_cvt_pk_fp8_f32(a, b, 0, false);
    w = __builtin_amdgcn_cvt_pk_fp8_f32(c, d, w, true);
    return (unsigned)w;
}
#else
__device__ __forceinline__ float sw_fp82f(unsigned v) {
    unsigned s = (v & 0x80u) << 24;
    unsigned e = (v >> 3) & 15u, m = v & 7u;
    float r = (e == 0) ? ((float)m * 0.001953125f)
                       : __uint_as_float(((e + 120u) << 23) | (m << 20));
    return __uint_as_float(s | __float_as_uint(r));
}
__device__ __forceinline__ f32x2 cvt2_lo(unsigned w) {
    return (f32x2){sw_fp82f(w & 255u), sw_fp82f((w >> 8) & 255u)};
}
__device__ __forceinline__ f32x2 cvt2_hi(unsigned w) {
    return (f32x2){sw_fp82f((w >> 16) & 255u), sw_fp82f(w >> 24)};
}
__device__ __forceinline__ unsigned sw_f2fp8(float f) {
    unsigned b = __float_as_uint(f);
    unsigned s = (b >> 24) & 0x80u;
    float af = fabsf(f);
    if (af < 0.0009765625f) return s;
    if (af >= 448.f) return s | 0x7Eu;
    int e = (int)((b >> 23) & 255u) - 127;
    if (e < -6) {
        int q = (int)rintf(af * 512.f);
        return s | (unsigned)q;
    }
    unsigned man = b & 0x7FFFFFu;
    unsigned r = (man + 0x7FFFFu + ((man >> 20) & 1u)) >> 20;
    unsigned enc = ((unsigned)(e + 7) << 3) + r;
    if (enc >= 0x7Fu) enc = 0x7Eu;
    return s | enc;
}
__device__ __forceinline__ unsigned pk_fp8x4(float a, float b, float c, float d) {
    return sw_f2fp8(a) | (sw_f2fp8(b) << 8) | (sw_f2fp8(c) << 16) | (sw_f2fp8(d) << 24);
}
#endif

// ---------------- init: cast x -> bf16+fp8, weights -> transposed bf16 ----------------
// (+1 trailing block initializes bkt_cur[b]=b*CAP and zeroes dcnt — replaces memset)
#define CAST_BLOCKS 6250   // NN*16/256
#define PREP_BLOCKS 200    // (16384+32768+2048)/256
__global__ void k_init(const float4* __restrict__ x4, uint2* __restrict__ xb,
                       unsigned* __restrict__ xb8,
                       const float* __restrict__ w1l, const float* __restrict__ w1r,
                       const float* __restrict__ w2l, const float* __restrict__ w2r,
                       const float* __restrict__ wfc,
                       unsigned short* __restrict__ W1T, unsigned short* __restrict__ W2T,
                       unsigned short* __restrict__ wfcT,
                       int* __restrict__ bkt_cur, int* __restrict__ dcnt) {
    int b = blockIdx.x, t = threadIdx.x;
    if (b >= CAST_BLOCKS + PREP_BLOCKS) {   // control-array init block
        for (int i = t; i < NBK + 1; i += 256) bkt_cur[i] = i * CAP;
        if (t < 64) dcnt[t] = 0;
        return;
    }
    if (b < CAST_BLOCKS) {
        int i = b * 256 + t;
        float4 v = x4[i];
        uint2 o;
        o.x = (unsigned)f2bf(v.x) | ((unsigned)f2bf(v.y) << 16);
        o.y = (unsigned)f2bf(v.z) | ((unsigned)f2bf(v.w) << 16);
        xb[i] = o;
        xb8[i] = pk_fp8x4(v.x, v.y, v.z, v.w);
        return;
    }
    int u = (b - CAST_BLOCKS) * 256 + t;
    if (u < 16384) {
        int n = u >> 7, k = u & 127;
        float v = (k < 64) ? w1l[k * 128 + n] : w1r[(k - 64) * 128 + n];
        W1T[u] = f2bf(v);
    } else if (u < 16384 + 32768) {
        int u2 = u - 16384;
        int n = u2 >> 8, kk = u2 & 255;
        float v;
        if (kk < 128) {
            int pk = (kk & 7) * 16 + (kk >> 3);   // permuted lin_l K-row (matches a2b)
            v = w2l[pk * 128 + n];
        } else {
            v = w2r[(kk - 128) * 128 + n];        // STANDARD K (matches std h1b; k_wfix rescales)
        }
        W2T[u2] = f2bf(v);
    } else {
        int u3 = u - 16384 - 32768;
        int o = u3 >> 7, k = u3 & 127;
        wfcT[u3] = f2bf(wfc[k * 16 + o]);         // standard K (Asm holds std cols)
    }
}

// ---------------- CSR build: fixed-capacity buckets (no hist/scan passes) ----
// bucket b = dst>>8 owns csr/packed range [b*CAP, b*CAP+count); bkt_cur pre-set to b*CAP.
__global__ __launch_bounds__(256) void k_part(const int* __restrict__ ei,
                                              int* __restrict__ bkt_cur,
                                              unsigned* __restrict__ packed) {
    __shared__ int lc[NBK];
    __shared__ int gb[NBK];
    int t = threadIdx.x;
    for (int i = t; i < NBK; i += 256) lc[i] = 0;
    __syncthreads();
    int e0 = blockIdx.x * EPB;
    int e1 = e0 + EPB; if (e1 > NE) e1 = NE;
    for (int e = e0 + t; e < e1; e += 256) {
        int d = ei[NE + e];
        atomicAdd(&lc[d >> 8], 1);
    }
    __syncthreads();
    for (int i = t; i < NBK; i += 256) {
        int c = lc[i];
        gb[i] = c ? atomicAdd(&bkt_cur[i], c) : 0;  // reserve per-(block,bucket) range
        lc[i] = 0;
    }
    __syncthreads();
    for (int e = e0 + t; e < e1; e += 256) {
        int d = ei[NE + e];
        int s = ei[e];
        int b = d >> 8;
        int r = atomicAdd(&lc[b], 1);               // local rank (LDS)
        packed[gb[b] + r] = (unsigned)s | ((unsigned)(d & 255) << 17);
    }
}

__global__ __launch_bounds__(256) void k_bucket(const unsigned* __restrict__ packed,
                                                const int* __restrict__ bkt_cur,
                                                int* __restrict__ csr, int* __restrict__ deg,
                                                int* __restrict__ rp,
                                                int* __restrict__ dcnt) {
    __shared__ int cnt[256];
    __shared__ int off[256];
    __shared__ int dh[64];
    int b = blockIdx.x, t = threadIdx.x;
    int base = b * CAP, end = bkt_cur[b];
    cnt[t] = 0;
    if (t < 64) dh[t] = 0;
    __syncthreads();
    for (int i = base + t; i < end; i += 256) {
        unsigned u = packed[i];
        atomicAdd(&cnt[u >> 17], 1);
    }
    __syncthreads();
    int v = cnt[t];
    int node = b * 256 + t;
    if (node < NN) atomicAdd(&dh[v < 63 ? v : 63], 1);
    off[t] = v;
    __syncthreads();
    for (int o = 1; o < 256; o <<= 1) {
        int u = (t >= o) ? off[t - o] : 0;
        __syncthreads();
        off[t] += u;
        __syncthreads();
    }
    int excl = off[t] - v;                 // exclusive prefix within bucket
    if (node < NN) {
        deg[node] = v;
        rp[node] = base + excl;
    }
    cnt[t] = base + excl;                  // reuse as scatter cursor
    __syncthreads();
    for (int i = base + t; i < end; i += 256) {
        unsigned u = packed[i];
        int p = atomicAdd(&cnt[u >> 17], 1);
        csr[p] = (int)(u & 0x1FFFFu);
    }
    if (t < 64 && dh[t]) atomicAdd(&dcnt[t], dh[t]);
}

__global__ void k_dscan(const int* __restrict__ dcnt, int* __restrict__ dcur) {
    __shared__ int s[64];
    int t = threadIdx.x;
    int v = dcnt[t];
    s[t] = v;
    __syncthreads();
    for (int o = 1; o < 64; o <<= 1) {
        int u = (t >= o) ? s[t - o] : 0;
        __syncthreads();
        s[t] += u;
        __syncthreads();
    }
    dcur[t] = s[t] - v;
}

__global__ __launch_bounds__(256) void k_dperm(const int* __restrict__ deg,
                                               const int* __restrict__ rp,
                                               int* __restrict__ dcur,
                                               uint2* __restrict__ perm) {
    __shared__ int lc[64];
    __shared__ int gb[64];
    int t = threadIdx.x;
    if (t < 64) lc[t] = 0;
    __syncthreads();
    int node = blockIdx.x * 256 + t;
    int bin = 0, r = 0, d = 0;
    bool ok = node < NN;
    if (ok) {
        d = deg[node];
        bin = d < 63 ? d : 63;
        r = atomicAdd(&lc[bin], 1);
    }
    __syncthreads();
    if (t < 64) gb[t] = lc[t] ? atomicAdd(&dcur[t], lc[t]) : 0;
    __syncthreads();
    if (ok) perm[gb[bin] + r] = make_uint2((unsigned)node | ((unsigned)d << 17),
                                           (unsigned)rp[node]);
}

// ---------------- gather layer 1 (fp8): agg1b[n] = bf16(mean x[s]) ----------------
__global__ __launch_bounds__(256) void k_agg1(
    const uint4* __restrict__ xb8, const int* __restrict__ csr,
    const uint2* __restrict__ perm, uint4* __restrict__ agg1b) {
    int t = threadIdx.x;
    int lane = t & 63;
    int grp = lane >> 2, f = lane & 3;
    int slot = blockIdx.x * 64 + (t >> 6) * 16 + grp;
    bool ok = slot < NN;
    uint2 pn = ok ? perm[slot] : make_uint2(0u, 0u);
    int node = (int)(pn.x & NMSK);
    int len = ok ? (int)(pn.x >> 17) : 0;
    const int* cp = csr + pn.y;
    f32x2 c[8];
#pragma unroll
    for (int k = 0; k < 8; k++) c[k] = (f32x2){0.f, 0.f};
    int s0 = cp[0] & NMSK, s1 = cp[1] & NMSK, s2 = cp[2] & NMSK, s3 = cp[3] & NMSK;
    int j = 0;
    while (j + 3 < len) {
        int n0 = cp[j + 4] & NMSK, n1 = cp[j + 5] & NMSK;
        int n2 = cp[j + 6] & NMSK, n3 = cp[j + 7] & NMSK;
        uint4 u0 = xb8[s0 * 4 + f];
        uint4 u1 = xb8[s1 * 4 + f];
        uint4 u2 = xb8[s2 * 4 + f];
        uint4 u3 = xb8[s3 * 4 + f];
        c[0] += cvt2_lo(u0.x); c[1] += cvt2_hi(u0.x); c[2] += cvt2_lo(u0.y); c[3] += cvt2_hi(u0.y);
        c[4] += cvt2_lo(u0.z); c[5] += cvt2_hi(u0.z); c[6] += cvt2_lo(u0.w); c[7] += cvt2_hi(u0.w);
        c[0] += cvt2_lo(u1.x); c[1] += cvt2_hi(u1.x); c[2] += cvt2_lo(u1.y); c[3] += cvt2_hi(u1.y);
        c[4] += cvt2_lo(u1.z); c[5] += cvt2_hi(u1.z); c[6] += cvt2_lo(u1.w); c[7] += cvt2_hi(u1.w);
        c[0] += cvt2_lo(u2.x); c[1] += cvt2_hi(u2.x); c[2] += cvt2_lo(u2.y); c[3] += cvt2_hi(u2.y);
        c[4] += cvt2_lo(u2.z); c[5] += cvt2_hi(u2.z); c[6] += cvt2_lo(u2.w); c[7] += cvt2_hi(u2.w);
        c[0] += cvt2_lo(u3.x); c[1] += cvt2_hi(u3.x); c[2] += cvt2_lo(u3.y); c[3] += cvt2_hi(u3.y);
        c[4] += cvt2_lo(u3.z); c[5] += cvt2_hi(u3.z); c[6] += cvt2_lo(u3.w); c[7] += cvt2_hi(u3.w);
        j += 4; s0 = n0; s1 = n1; s2 = n2; s3 = n3;
    }
    while (j < len) {
        uint4 u = xb8[s0 * 4 + f];
        c[0] += cvt2_lo(u.x); c[1] += cvt2_hi(u.x); c[2] += cvt2_lo(u.y); c[3] += cvt2_hi(u.y);
        c[4] += cvt2_lo(u.z); c[5] += cvt2_hi(u.z); c[6] += cvt2_lo(u.w); c[7] += cvt2_hi(u.w);
        s0 = s1; s1 = s2; s2 = s3; ++j;
    }
    float ic = 1.0f / fmaxf((float)len, 1.0f);
    uint4 o0, o1;
    o0.x = (unsigned)f2bf(c[0][0] * ic) | ((unsigned)f2bf(c[0][1] * ic) << 16);
    o0.y = (unsigned)f2bf(c[1][0] * ic) | ((unsigned)f2bf(c[1][1] * ic) << 16);
    o0.z = (unsigned)f2bf(c[2][0] * ic) | ((unsigned)f2bf(c[2][1] * ic) << 16);
    o0.w = (unsigned)f2bf(c[3][0] * ic) | ((unsigned)f2bf(c[3][1] * ic) << 16);
    o1.x = (unsigned)f2bf(c[4][0] * ic) | ((unsigned)f2bf(c[4][1] * ic) << 16);
    o1.y = (unsigned)f2bf(c[5][0] * ic) | ((unsigned)f2bf(c[5][1] * ic) << 16);
    o1.z = (unsigned)f2bf(c[6][0] * ic) | ((unsigned)f2bf(c[6][1] * ic) << 16);
    o1.w = (unsigned)f2bf(c[7][0] * ic) | ((unsigned)f2bf(c[7][1] * ic) << 16);
    if (ok) {
        agg1b[node * 8 + f * 2] = o0;
        agg1b[node * 8 + f * 2 + 1] = o1;
    }
}

// ---------------- gather layer 2 (fp8, permuted cols) + BN fold ----------------
__global__ __launch_bounds__(256) void k_agg2(
    const uint4* __restrict__ h1f8, const int* __restrict__ csr,
    const float* __restrict__ statsp, const uint2* __restrict__ perm,
    uint4* __restrict__ a2b) {
    int t = threadIdx.x;
    int lane = t & 63;
    int grp = lane >> 3, f = lane & 7;
    int slot = blockIdx.x * 32 + (t >> 6) * 8 + grp;   // NN % 32 == 0
    uint2 pn = perm[slot];
    int node = (int)(pn.x & NMSK);
    int len = (int)(pn.x >> 17);
    const int* cp = csr + pn.y;
    f32x2 c[8];
#pragma unroll
    for (int k = 0; k < 8; k++) c[k] = (f32x2){0.f, 0.f};
    int s0 = cp[0] & NMSK, s1 = cp[1] & NMSK, s2 = cp[2] & NMSK, s3 = cp[3] & NMSK;
    int j = 0;
    while (j + 3 < len) {
        int n0 = cp[j + 4] & NMSK, n1 = cp[j + 5] & NMSK;
        int n2 = cp[j + 6] & NMSK, n3 = cp[j + 7] & NMSK;
        uint4 u0 = h1f8[s0 * 8 + f];
        uint4 u1 = h1f8[s1 * 8 + f];
        uint4 u2 = h1f8[s2 * 8 + f];
        uint4 u3 = h1f8[s3 * 8 + f];
        c[0] += cvt2_lo(u0.x); c[1] += cvt2_hi(u0.x); c[2] += cvt2_lo(u0.y); c[3] += cvt2_hi(u0.y);
        c[4] += cvt2_lo(u0.z); c[5] += cvt2_hi(u0.z); c[6] += cvt2_lo(u0.w); c[7] += cvt2_hi(u0.w);
        c[0] += cvt2_lo(u1.x); c[1] += cvt2_hi(u1.x); c[2] += cvt2_lo(u1.y); c[3] += cvt2_hi(u1.y);
        c[4] += cvt2_lo(u1.z); c[5] += cvt2_hi(u1.z); c[6] += cvt2_lo(u1.w); c[7] += cvt2_hi(u1.w);
        c[0] += cvt2_lo(u2.x); c[1] += cvt2_hi(u2.x); c[2] += cvt2_lo(u2.y); c[3] += cvt2_hi(u2.y);
        c[4] += cvt2_lo(u2.z); c[5] += cvt2_hi(u2.z); c[6] += cvt2_lo(u2.w); c[7] += cvt2_hi(u2.w);
        c[0] += cvt2_lo(u3.x); c[1] += cvt2_hi(u3.x); c[2] += cvt2_lo(u3.y); c[3] += cvt2_hi(u3.y);
        c[4] += cvt2_lo(u3.z); c[5] += cvt2_hi(u3.z); c[6] += cvt2_lo(u3.w); c[7] += cvt2_hi(u3.w);
        j += 4; s0 = n0; s1 = n1; s2 = n2; s3 = n3;
    }
    while (j < len) {
        uint4 u = h1f8[s0 * 8 + f];
        c[0] += cvt2_lo(u.x); c[1] += cvt2_hi(u.x); c[2] += cvt2_lo(u.y); c[3] += cvt2_hi(u.y);
        c[4] += cvt2_lo(u.z); c[5] += cvt2_hi(u.z); c[6] += cvt2_lo(u.w); c[7] += cvt2_hi(u.w);
        s0 = s1; s1 = s2; s2 = s3; ++j;
    }
    float ic = 1.0f / fmaxf((float)len, 1.0f);
    float hv = (len > 0) ? 1.0f : 0.0f;
    const float4* sc4 = (const float4*)statsp;
    const float4* sh4 = (const float4*)(statsp + 128);
    float v[16];
#pragma unroll
    for (int q = 0; q < 4; q++) {
        float4 sc = sc4[f * 4 + q];
        float4 sh = sh4[f * 4 + q];
        v[q * 4 + 0] = c[q * 2][0] * ic * sc.x + sh.x * hv;
        v[q * 4 + 1] = c[q * 2][1] * ic * sc.y + sh.y * hv;
        v[q * 4 + 2] = c[q * 2 + 1][0] * ic * sc.z + sh.z * hv;
        v[q * 4 + 3] = c[q * 2 + 1][1] * ic * sc.w + sh.w * hv;
    }
    uint4 o0, o1;
    o0.x = (unsigned)f2bf(v[0]) | ((unsigned)f2bf(v[1]) << 16);
    o0.y = (unsigned)f2bf(v[2]) | ((unsigned)f2bf(v[3]) << 16);
    o0.z = (unsigned)f2bf(v[4]) | ((unsigned)f2bf(v[5]) << 16);
    o0.w = (unsigned)f2bf(v[6]) | ((unsigned)f2bf(v[7]) << 16);
    o1.x = (unsigned)f2bf(v[8]) | ((unsigned)f2bf(v[9]) << 16);
    o1.y = (unsigned)f2bf(v[10]) | ((unsigned)f2bf(v[11]) << 16);
    o1.z = (unsigned)f2bf(v[12]) | ((unsigned)f2bf(v[13]) << 16);
    o1.w = (unsigned)f2bf(v[14]) | ((unsigned)f2bf(v[15]) << 16);
    a2b[node * 16 + f * 2] = o0;
    a2b[node * 16 + f * 2 + 1] = o1;
}

// ---------------- layer 1 MFMA (proven form + next-tile A prefetch) ----
__global__ __launch_bounds__(256, 3) void k_gemm1(
    const uint4* __restrict__ agg1b, const uint4* __restrict__ xb,
    const uint4* __restrict__ W1T, const float* __restrict__ b1l,
    uint4* __restrict__ h1b, uint2* __restrict__ h1f8, float* __restrict__ part) {
    __shared__ unsigned short Wsm[128 * LDA];  // 34816 B
    __shared__ unsigned short Asm[64 * LDA];   // 17408 B
    __shared__ float cs[128], cq[128];
    const int t = threadIdx.x;
    const int w = t >> 6, lane = t & 63, quad = lane >> 4, l15 = lane & 15;
    if (t < 128) { cs[t] = 0.f; cq[t] = 0.f; }
    {   // stage W1T once (row=256B=16 uint4)
        int r = t >> 1, h = t & 1;
#pragma unroll
        for (int i = 0; i < 8; i++) {
            uint4 v = W1T[r * 16 + h * 8 + i];
            *(uint4*)&Wsm[r * LDA + h * 64 + i * 8] = v;
        }
    }
    float bias[8];
#pragma unroll
    for (int nt = 0; nt < 8; nt++) bias[nt] = b1l[nt * 16 + l15];
    float colsum[8] = {0, 0, 0, 0, 0, 0, 0, 0};
    float colsq[8]  = {0, 0, 0, 0, 0, 0, 0, 0};
    const int arow = 16 * w + l15;          // this lane's A-fragment row
    __syncthreads();                        // W staged, cs/cq init

    Q16 af[4];
    {
        const int base0 = blockIdx.x * 64;
        const int valid0 = (NN - base0 < 64) ? (NN - base0) : 64;
        const int gm0 = base0 + arow;
        const bool ok0 = arow < valid0;
#pragma unroll
        for (int kc = 0; kc < 2; kc++)
            af[kc].q = ok0 ? agg1b[gm0 * 8 + kc * 4 + quad] : make_uint4(0, 0, 0, 0);
#pragma unroll
        for (int kc = 0; kc < 2; kc++)
            af[2 + kc].q = ok0 ? xb[gm0 * 8 + kc * 4 + quad] : make_uint4(0, 0, 0, 0);
    }

    for (int g = blockIdx.x; g < NT1; g += gridDim.x) {
        const int base = g * 64;
        const int valid = (NN - base < 64) ? (NN - base) : 64;
        f32x4 acc[8];
#pragma unroll
        for (int nt = 0; nt < 8; nt++) acc[nt] = (f32x4){bias[nt], bias[nt], bias[nt], bias[nt]};
#pragma unroll
        for (int kc = 0; kc < 4; kc++) {
#pragma unroll
            for (int nt = 0; nt < 8; nt++) {
                s16x8 bf = *(const s16x8*)&Wsm[(nt * 16 + l15) * LDA + kc * 32 + quad * 8];
                acc[nt] = __builtin_amdgcn_mfma_f32_16x16x32_bf16(af[kc].v, bf, acc[nt], 0, 0, 0);
            }
        }
        {   // prefetch next tile's A-fragments (af dead after MFMA)
            const int gn = g + gridDim.x;
            const bool okg = gn < NT1;
            const int basen = okg ? gn * 64 : 0;
            const int validn = (NN - basen < 64) ? (NN - basen) : 64;
            const int gmn = basen + arow;
            const bool okn = okg && (arow < validn);
#pragma unroll
            for (int kc = 0; kc < 2; kc++)
                af[kc].q = okn ? agg1b[gmn * 8 + kc * 4 + quad] : make_uint4(0, 0, 0, 0);
#pragma unroll
            for (int kc = 0; kc < 2; kc++)
                af[2 + kc].q = okn ? xb[gmn * 8 + kc * 4 + quad] : make_uint4(0, 0, 0, 0);
        }
        // epilogue: norm+relu+stats; bf16 into Asm (std cols); fp8 direct (permuted)
        float ssr[4] = {0, 0, 0, 0};
#pragma unroll
        for (int nt = 0; nt < 8; nt++)
#pragma unroll
            for (int r = 0; r < 4; r++) ssr[r] += acc[nt][r] * acc[nt][r];
#pragma unroll
        for (int r = 0; r < 4; r++) {
            ssr[r] += __shfl_xor(ssr[r], 1); ssr[r] += __shfl_xor(ssr[r], 2);
            ssr[r] += __shfl_xor(ssr[r], 4); ssr[r] += __shfl_xor(ssr[r], 8);
        }
#pragma unroll
        for (int r = 0; r < 4; r++) {
            int mrow = 16 * w + quad * 4 + r;
            float iv = 1.0f / fmaxf(sqrtf(ssr[r]), 1e-12f);
            bool okr = mrow < valid;
            float v[8];
#pragma unroll
            for (int nt = 0; nt < 8; nt++) {
                float vv = fmaxf(acc[nt][r] * iv, 0.f);
                if (!okr) vv = 0.f;
                v[nt] = vv;
                colsum[nt] += vv;
                colsq[nt] += vv * vv;
                Asm[mrow * LDA + nt * 16 + l15] = f2bf(vv);
            }
            if (okr) {
                uint2 o;
                o.x = pk_fp8x4(v[0], v[1], v[2], v[3]);
                o.y = pk_fp8x4(v[4], v[5], v[6], v[7]);
                h1f8[(base + mrow) * 16 + l15] = o;   // permuted col' = l15*8+nt
            }
        }
        __syncthreads();
        {   // coalesced h1b store (row=256B=16 uint4), STANDARD layout
            int m = t >> 2, p = t & 3;
            if (m < valid) {
                int gm2 = base + m;
#pragma unroll
                for (int i = 0; i < 4; i++) {
                    uint4 v = *(const uint4*)&Asm[m * LDA + p * 32 + i * 8];
                    h1b[gm2 * 16 + p * 4 + i] = v;
                }
            }
        }
        __syncthreads();  // readback done before next epilogue overwrites Asm
    }
    __syncthreads();
#pragma unroll
    for (int nt = 0; nt < 8; nt++) {
        atomicAdd(&cs[nt * 16 + l15], colsum[nt]);
        atomicAdd(&cq[nt * 16 + l15], colsq[nt]);
    }
    __syncthreads();
    if (t < 128) {
        part[blockIdx.x * 256 + t] = cs[t];
        part[blockIdx.x * 256 + 128 + t] = cq[t];
    }
}

// ---------------- BN finalize: stats + permuted copy ----------------
__global__ void k_bnfin(const float* __restrict__ part, const float* __restrict__ gamma,
                        const float* __restrict__ beta, float* __restrict__ stats) {
    int t = threadIdx.x;  // 128 (channel)
    float s = 0.f, q = 0.f;
    for (int b = 0; b < PART_BLOCKS; b++) {
        s += part[b * 256 + t];
        q += part[b * 256 + 128 + t];
    }
    float mean = s / (float)NN;
    float var = q / (float)NN - mean * mean;
    float sc = gamma[t] * rsqrtf(var + 1e-5f);
    float sh = beta[t] - mean * sc;
    stats[t] = sc;
    stats[128 + t] = sh;
    int cp = (t & 15) * 8 + (t >> 4);   // permuted position of channel t
    stats[256 + cp] = sc;
    stats[384 + cp] = sh;
}

// ---------------- W2 fixup: fold BN scale into lin_r weights, shift into bias ----
__global__ void k_wfix(const float* __restrict__ w2r, const float* __restrict__ stats,
                       const float* __restrict__ b2l,
                       unsigned short* __restrict__ W2T, float* __restrict__ bias2) {
    __shared__ float sb[128];
    int n = blockIdx.x;       // 128 (output channel)
    int k = threadIdx.x;      // 128 (std K position = h1 channel)
    float wv = w2r[k * 128 + n];
    W2T[n * 256 + 128 + k] = f2bf(wv * stats[k]);
    sb[k] = stats[128 + k] * wv;                    // sh[k] * w2r[k][n]
    __syncthreads();
    for (int o = 64; o > 0; o >>= 1) {
        if (k < o) sb[k] += sb[k + o];
        __syncthreads();
    }
    if (k == 0) bias2[n] = b2l[n] + sb[0];
}

// ---------------- layer 2 MFMA (K=256) + L2norm + FC (proven form + prefetch) ----
__global__ __launch_bounds__(512) void k_gemm2(
    const uint4* __restrict__ a2b, const uint4* __restrict__ h1b,
    const uint4* __restrict__ W2T, const float* __restrict__ bias2,
    const uint4* __restrict__ wfcT, const float* __restrict__ bfc,
    float* __restrict__ out) {
    __shared__ unsigned short WsmF[128 * LDW];   // 67584 B (full W2T [N=128][K=256])
    __shared__ unsigned short Asm[128 * LDA];    // 34816 B (h2 for FC redistribution)
    __shared__ unsigned short wfcsm[16 * LDA];   // 4352 B
    const int t = threadIdx.x;
    const int w = t >> 6, lane = t & 63, quad = lane >> 4, l15 = lane & 15;

    {   // full W2T: row r (N), 512B = 32 uint4
        int r = t >> 2, seg = t & 3;
#pragma unroll
        for (int i = 0; i < 8; i++) {
            uint4 v = W2T[r * 32 + seg * 8 + i];
            *(uint4*)&WsmF[r * LDW + (seg * 8 + i) * 8] = v;
        }
    }
    if (t < 64) {   // wfcT: 16 rows x 256B
        int n = t >> 2, p = t & 3;
#pragma unroll
        for (int i = 0; i < 4; i++) {
            uint4 v = wfcT[n * 16 + p * 4 + i];
            *(uint4*)&wfcsm[n * LDA + p * 32 + i * 8] = v;
        }
    }
    float bias[8];
#pragma unroll
    for (int nt = 0; nt < 8; nt++) bias[nt] = bias2[nt * 16 + l15];
    const float fb = bfc[l15];
    const int arow = 16 * w + l15;          // 0..127
    __syncthreads();

    Q16 af[8];
    {
        const int base0 = blockIdx.x * 128;
        const int valid0 = (NN - base0 < 128) ? (NN - base0) : 128;
        const int gm0 = base0 + arow;
        const bool ok0 = arow < valid0;
#pragma unroll
        for (int kc = 0; kc < 4; kc++)
            af[kc].q = ok0 ? a2b[gm0 * 16 + kc * 4 + quad] : make_uint4(0, 0, 0, 0);
#pragma unroll
        for (int kc = 0; kc < 4; kc++)
            af[4 + kc].q = ok0 ? h1b[gm0 * 16 + kc * 4 + quad] : make_uint4(0, 0, 0, 0);
    }

    for (int g = blockIdx.x; g < NT2; g += gridDim.x) {
        const int base = g * 128;
        const int valid = (NN - base < 128) ? (NN - base) : 128;

        f32x4 acc[8];
#pragma unroll
        for (int nt = 0; nt < 8; nt++) acc[nt] = (f32x4){bias[nt], bias[nt], bias[nt], bias[nt]};
#pragma unroll
        for (int kc = 0; kc < 8; kc++) {
#pragma unroll
            for (int nt = 0; nt < 8; nt++) {
                s16x8 bf = *(const s16x8*)&WsmF[(nt * 16 + l15) * LDW + kc * 32 + quad * 8];
                acc[nt] = __builtin_amdgcn_mfma_f32_16x16x32_bf16(af[kc].v, bf, acc[nt], 0, 0, 0);
            }
        }
        {   // prefetch next tile's A-fragments (af dead after MFMA)
            const int gn = g + gridDim.x;
            const bool okg = gn < NT2;
            const int basen = okg ? gn * 128 : 0;
            const int validn = (NN - basen < 128) ? (NN - basen) : 128;
            const int gmn = basen + arow;
            const bool okn = okg && (arow < validn);
#pragma unroll
            for (int kc = 0; kc < 4; kc++)
                af[kc].q = okn ? a2b[gmn * 16 + kc * 4 + quad] : make_uint4(0, 0, 0, 0);
#pragma unroll
            for (int kc = 0; kc < 4; kc++)
                af[4 + kc].q = okn ? h1b[gmn * 16 + kc * 4 + quad] : make_uint4(0, 0, 0, 0);
        }

        // epilogue: L2 norm, h2 -> Asm (standard col positions)
        float ssr[4] = {0, 0, 0, 0};
#pragma unroll
        for (int nt = 0; nt < 8; nt++)
#pragma unroll
            for (int r = 0; r < 4; r++) ssr[r] += acc[nt][r] * acc[nt][r];
#pragma unroll
        for (int r = 0; r < 4; r++) {
            ssr[r] += __shfl_xor(ssr[r], 1); ssr[r] += __shfl_xor(ssr[r], 2);
            ssr[r] += __shfl_xor(ssr[r], 4); ssr[r] += __shfl_xor(ssr[r], 8);
        }
#pragma unroll
        for (int r = 0; r < 4; r++) {
            int mrow = 16 * w + quad * 4 + r;
            float iv = 1.0f / fmaxf(sqrtf(ssr[r]), 1e-12f);
#pragma unroll
            for (int nt = 0; nt < 8; nt++) {
                Asm[mrow * LDA + nt * 16 + l15] = f2bf(acc[nt][r] * iv);
            }
        }
        __syncthreads();   // h2 complete
        // FC: 16x16 tile per wave, K=128
        f32x4 a2 = (f32x4){fb, fb, fb, fb};
#pragma unroll
        for (int kc = 0; kc < 4; kc++) {
            s16x8 af2 = *(const s16x8*)&Asm[arow * LDA + kc * 32 + quad * 8];
            s16x8 bf2 = *(const s16x8*)&wfcsm[l15 * LDA + kc * 32 + quad * 8];
            a2 = __builtin_amdgcn_mfma_f32_16x16x32_bf16(af2, bf2, a2, 0, 0, 0);
        }
#pragma unroll
        for (int r = 0; r < 4; r++) {
            int mrow = 16 * w + quad * 4 + r;
            if (mrow < valid) out[(base + mrow) * 16 + l15] = a2[r];
        }
        __syncthreads();   // FC reads done before next tile overwrites Asm
    }
}

extern "C" void kernel_launch(void* const* d_in, const int* in_sizes, int n_in,
                              void* d_out, int out_size, void* d_ws, size_t ws_size,
                              hipStream_t stream) {
    const float* x     = (const float*)d_in[0];
    const int*   ei    = (const int*)d_in[1];
    const float* w1l   = (const float*)d_in[2];
    const float* b1l   = (const float*)d_in[3];
    const float* w1r   = (const float*)d_in[4];
    const float* gamma = (const float*)d_in[5];
    const float* beta  = (const float*)d_in[6];
    const float* w2l   = (const float*)d_in[7];
    const float* b2l   = (const float*)d_in[8];
    const float* w2r   = (const float*)d_in[9];
    const float* wfc   = (const float*)d_in[10];
    const float* bfc   = (const float*)d_in[11];
    float* out = (float*)d_out;

    float* W = (float*)d_ws;
    int* bkt_cur  = (int*)(W + OFS_BKT) + 1024;   // [512] (pre-init by k_init to b*CAP)
    int* dcnt     = (int*)(W + OFS_BKT) + 1536;   // [64]
    int* dcur     = (int*)(W + OFS_BKT) + 1600;   // [64]
    int* deg   = (int*)(W + OFS_DEG);
    int* rp    = (int*)(W + OFS_RP);
    float* bias2 = W + OFS_BSUM;                  // [128] fp32
    uint2* perm = (uint2*)(W + OFS_RANK);         // 2*NN words (fat records)
    int* csr   = (int*)(W + OFS_CSR);             // capacity layout: NBK*CAP words
    unsigned* xb   = (unsigned*)(W + OFS_XB);
    unsigned* xb8  = (unsigned*)(W + OFS_XB8);
    unsigned* a1b  = (unsigned*)(W + OFS_A1B);
    unsigned* h1b  = (unsigned*)(W + OFS_H1B);
    unsigned* h1f8 = (unsigned*)(W + OFS_H1F8);
    unsigned* a2b  = (unsigned*)(W + OFS_A2B);
    unsigned* packed = (unsigned*)(W + OFS_A2B);  // NBK*CAP words; dead before k_agg2 writes a2b
    unsigned short* W1T  = (unsigned short*)(W + OFS_W1T);
    unsigned short* W2T  = (unsigned short*)(W + OFS_W2T);
    unsigned short* wfcT = (unsigned short*)(W + OFS_WFCT);
    float* stats = W + OFS_STATS;          // [sc|sh|sc'|sh'] (512)
    float* part  = W + OFS_PART;

    k_init<<<CAST_BLOCKS + PREP_BLOCKS + 1, 256, 0, stream>>>(
        (const float4*)x, (uint2*)xb, xb8, w1l, w1r, w2l, w2r, wfc, W1T, W2T, wfcT,
        bkt_cur, dcnt);
    k_part  <<<NPB, 256, 0, stream>>>(ei, bkt_cur, packed);
    k_bucket<<<NBK, 256, 0, stream>>>(packed, bkt_cur, csr, deg, rp, dcnt);
    k_dscan <<<1, 64, 0, stream>>>(dcnt, dcur);
    k_dperm <<<NBK, 256, 0, stream>>>(deg, rp, dcur, perm);

    k_agg1 <<<(NN + 63) / 64, 256, 0, stream>>>((const uint4*)xb8, csr, perm, (uint4*)a1b);
    k_gemm1<<<PART_BLOCKS, 256, 0, stream>>>((const uint4*)a1b, (const uint4*)xb,
                                             (const uint4*)W1T, b1l, (uint4*)h1b,
                                             (uint2*)h1f8, part);
    k_bnfin<<<1, 128, 0, stream>>>(part, gamma, beta, stats);
    k_wfix <<<128, 128, 0, stream>>>(w2r, stats, b2l, W2T, bias2);
    k_agg2 <<<NN / 32, 256, 0, stream>>>((const uint4*)h1f8, csr, stats + 256, perm,
                                         (uint4*)a2b);
    k_gemm2<<<256, 512, 0, stream>>>((const uint4*)a2b, (const uint4*)h1b,
                                     (const uint4*)W2T, bias2, (const uint4*)wfcT,
                                     bfc, out);
}

// Round 13
// 283.123 us; speedup vs baseline: 1.3181x; 1.0369x over previous
//
#include <hip/hip_runtime.h>
#include <math.h>

#define NN 100000
#define NE 1600000
#define PART_BLOCKS 768
#define NT1 1563          // ceil(NN/64)  M-tiles (gemm1)
#define NT2 391           // ceil(NN/256) M-tiles (gemm2, 256-row tiles)
#define LDA 136           // padded LDS row stride (ushorts): 272 B, 16B-aligned
#define LDW 264           // padded W2T-full row stride (ushorts): 528 B
#define NMSK 0x1FFFF      // node-index mask (NN < 2^17); bounds derived addrs into ws

// ---- bucketed CSR build params ----
#define NBK 391           // ceil(NN/256) buckets of 256 dst nodes
#define EPB 4096          // edges per part block
#define NPB 391           // ceil(NE/EPB)
#define CAP 4600          // fixed bucket capacity: mean 4092, sd 64 -> mean+7.9sd.
                          // 391*4600=1,798,600 words fits csr region (NE+2*NN=1.8M).

typedef float f32x4 __attribute__((ext_vector_type(4)));
typedef float f32x2 __attribute__((ext_vector_type(2)));
typedef short s16x8 __attribute__((ext_vector_type(8)));

union Q16 { uint4 q; s16x8 v; };

// ---- ws layout (4-byte words) ----
#define OFS_BKT   0                     // (unused)[1024] | bkt_cur[512] | dcnt[64] | dcur[64]
#define OFS_DEG   (8*NN)                // int[NN]
#define OFS_RP    (9*NN)                // int[NN]
#define OFS_BSUM  (10*NN)               // reused: bias2[128] fp32 (b2l + sh·w2r)
#define OFS_RANK  (10*NN + 1024)        // reused: perm[NN] uint2 {node|deg<<17, rp} -> 2*NN words
#define OFS_CSR   (OFS_RANK + NE/2)     // capacity-layout csr: NBK*CAP words (extends into dead INV/HAS)
#define OFS_INV   (OFS_CSR + NE)        // dead (absorbed by csr capacity layout)
#define OFS_HAS   (OFS_INV + NN)        // dead (absorbed by csr capacity layout)
#define OFS_XB    (OFS_HAS + NN)        // x bf16 [NN][64]   -> 32*NN words
#define OFS_XB8   (OFS_XB + 32*NN)      // x fp8 [NN][64]    -> 16*NN words
#define OFS_A1B   (OFS_XB8 + 16*NN)     // agg1 bf16 [NN][64]-> 32*NN
#define OFS_H1B   (OFS_A1B + 32*NN)     // h1 bf16 STANDARD cols [NN][128] -> 64*NN
#define OFS_H1F8  (OFS_H1B + 64*NN)     // h1 fp8 PERMUTED [NN][128] -> 32*NN
#define OFS_A2B   (OFS_H1F8 + 32*NN)    // BN'd agg2 bf16 PERMUTED [NN][128] -> 64*NN
                                        //   (also reused EARLY as packed-edge buffer, NBK*CAP words)
#define OFS_W1T   (OFS_A2B + 64*NN)     // [128][128] ush -> 8192 words
#define OFS_W2T   (OFS_W1T + 8192)      // [128][256] ush (a2b-half K permuted; h1-half K STANDARD, sc-scaled by k_wfix) -> 16384
#define OFS_WFCT  (OFS_W2T + 16384)     // [16][128] ush (K standard) -> 1024 words
#define OFS_STATS (OFS_WFCT + 1024)     // 512: [sc 128][sh 128][sc' 128][sh' 128]
#define OFS_PART  (OFS_STATS + 512)     // 768*256

// col permutation: c' = l15*8 + nt  <->  c = nt*16 + l15  (P(c') = (c'&7)*16 + (c'>>3))
// stats[256+c'] = sc[P(c')], stats[384+c'] = sh[P(c')]
// NOTE (empirical, rounds 5-10): per-tile __syncthreads in the persistent MFMA loops
// are LOAD-BEARING FOR L2 LOCALITY — removing them desyncs waves and blows HBM
// traffic ~2.5x (FETCH 74->116MB signatures). Do not remove.

__device__ __forceinline__ unsigned short f2bf(float f) {
    unsigned u = __float_as_uint(f);
    return (unsigned short)((u + 0x7FFFu + ((u >> 16) & 1u)) >> 16);
}
__device__ __forceinline__ float bfl(unsigned u) { return __uint_as_float(u << 16); }
__device__ __forceinline__ float bfh(unsigned u) { return __uint_as_float(u & 0xFFFF0000u); }

// ---- fp8 e4m3 pack/unpack (HW cvt on gfx950; software fallback) ----
#if __has_builtin(__builtin_amdgcn_cvt_pk_f32_fp8) && __has_builtin(__builtin_amdgcn_cvt_pk_fp8_f32)
__device__ __forceinline__ f32x2 cvt2_lo(unsigned w) {
    return __builtin_amdgcn_cvt_pk_f32_fp8((int)w, false);
}
__device__ __forceinline__ f32x2 cvt2_hi(unsigned w) {
    return __builtin_amdgcn_cvt_pk_f32_fp8((int)w, true);
}
__device__ __forceinline__ unsigned pk_fp8x4(float a, float b, float c, float d) {
    int w = __builtin_amdgcn_cvt_pk_fp8_f32(a, b, 0, false);
    w = __builtin_amdgcn_cvt_pk_fp8_f32(c, d, w, true);
    return (unsigned)w;
}
#else
__device__ __forceinline__ float sw_fp82f(unsigned v) {
    unsigned s = (v & 0x80u) << 24;
    unsigned e = (v >> 3) & 15u, m = v & 7u;
    float r = (e == 0) ? ((float)m * 0.001953125f)
                       : __uint_as_float(((e + 120u) << 23) | (m << 20));
    return __uint_as_float(s | __float_as_uint(r));
}
__device__ __forceinline__ f32x2 cvt2_lo(unsigned w) {
    return (f32x2){sw_fp82f(w & 255u), sw_fp82f((w >> 8) & 255u)};
}
__device__ __forceinline__ f32x2 cvt2_hi(unsigned w) {
    return (f32x2){sw_fp82f((w >> 16) & 255u), sw_fp82f(w >> 24)};
}
__device__ __forceinline__ unsigned sw_f2fp8(float f) {
    unsigned b = __float_as_uint(f);
    unsigned s = (b >> 24) & 0x80u;
    float af = fabsf(f);
    if (af < 0.0009765625f) return s;
    if (af >= 448.f) return s | 0x7Eu;
    int e = (int)((b >> 23) & 255u) - 127;
    if (e < -6) {
        int q = (int)rintf(af * 512.f);
        return s | (unsigned)q;
    }
    unsigned man = b & 0x7FFFFFu;
    unsigned r = (man + 0x7FFFFu + ((man >> 20) & 1u)) >> 20;
    unsigned enc = ((unsigned)(e + 7) << 3) + r;
    if (enc >= 0x7Fu) enc = 0x7Eu;
    return s | enc;
}
__device__ __forceinline__ unsigned pk_fp8x4(float a, float b, float c, float d) {
    return sw_f2fp8(a) | (sw_f2fp8(b) << 8) | (sw_f2fp8(c) << 16) | (sw_f2fp8(d) << 24);
}
#endif

// ---------------- init: cast x -> bf16+fp8, weights -> transposed bf16 ----------------
// (+1 trailing block initializes bkt_cur[b]=b*CAP and zeroes dcnt — replaces memset)
#define CAST_BLOCKS 6250   // NN*16/256
#define PREP_BLOCKS 200    // (16384+32768+2048)/256
__global__ void k_init(const float4* __restrict__ x4, uint2* __restrict__ xb,
                       unsigned* __restrict__ xb8,
                       const float* __restrict__ w1l, const float* __restrict__ w1r,
                       const float* __restrict__ w2l, const float* __restrict__ w2r,
                       const float* __restrict__ wfc,
                       unsigned short* __restrict__ W1T, unsigned short* __restrict__ W2T,
                       unsigned short* __restrict__ wfcT,
                       int* __restrict__ bkt_cur, int* __restrict__ dcnt) {
    int b = blockIdx.x, t = threadIdx.x;
    if (b >= CAST_BLOCKS + PREP_BLOCKS) {   // control-array init block
        for (int i = t; i < NBK + 1; i += 256) bkt_cur[i] = i * CAP;
        if (t < 64) dcnt[t] = 0;
        return;
    }
    if (b < CAST_BLOCKS) {
        int i = b * 256 + t;
        float4 v = x4[i];
        uint2 o;
        o.x = (unsigned)f2bf(v.x) | ((unsigned)f2bf(v.y) << 16);
        o.y = (unsigned)f2bf(v.z) | ((unsigned)f2bf(v.w) << 16);
        xb[i] = o;
        xb8[i] = pk_fp8x4(v.x, v.y, v.z, v.w);
        return;
    }
    int u = (b - CAST_BLOCKS) * 256 + t;
    if (u < 16384) {
        int n = u >> 7, k = u & 127;
        float v = (k < 64) ? w1l[k * 128 + n] : w1r[(k - 64) * 128 + n];
        W1T[u] = f2bf(v);
    } else if (u < 16384 + 32768) {
        int u2 = u - 16384;
        int n = u2 >> 8, kk = u2 & 255;
        float v;
        if (kk < 128) {
            int pk = (kk & 7) * 16 + (kk >> 3);   // permuted lin_l K-row (matches a2b)
            v = w2l[pk * 128 + n];
        } else {
            v = w2r[(kk - 128) * 128 + n];        // STANDARD K (matches std h1b; k_wfix rescales)
        }
        W2T[u2] = f2bf(v);
    } else {
        int u3 = u - 16384 - 32768;
        int o = u3 >> 7, k = u3 & 127;
        wfcT[u3] = f2bf(wfc[k * 16 + o]);         // standard K (Asm holds std cols)
    }
}

// ---------------- CSR build: fixed-capacity buckets (no hist/scan passes) ----
// bucket b = dst>>8 owns csr/packed range [b*CAP, b*CAP+count); bkt_cur pre-set to b*CAP.
// Edges cached in registers (16/thread): ei read ONCE.
__global__ __launch_bounds__(256) void k_part(const int* __restrict__ ei,
                                              int* __restrict__ bkt_cur,
                                              unsigned* __restrict__ packed) {
    __shared__ int lc[NBK];
    __shared__ int gb[NBK];
    int t = threadIdx.x;
    for (int i = t; i < NBK; i += 256) lc[i] = 0;
    __syncthreads();
    int e0 = blockIdx.x * EPB;
    int e1 = e0 + EPB; if (e1 > NE) e1 = NE;
    int dc[16], sc[16];
#pragma unroll
    for (int i = 0; i < 16; i++) {
        int e = e0 + t + i * 256;
        bool ok = e < e1;
        dc[i] = ok ? ei[NE + e] : -1;
        sc[i] = ok ? ei[e] : 0;
        if (ok) atomicAdd(&lc[dc[i] >> 8], 1);
    }
    __syncthreads();
    for (int i = t; i < NBK; i += 256) {
        int c = lc[i];
        gb[i] = c ? atomicAdd(&bkt_cur[i], c) : 0;  // reserve per-(block,bucket) range
        lc[i] = 0;
    }
    __syncthreads();
#pragma unroll
    for (int i = 0; i < 16; i++) {
        if (dc[i] >= 0) {
            int b = dc[i] >> 8;
            int r = atomicAdd(&lc[b], 1);           // local rank (LDS)
            packed[gb[b] + r] = (unsigned)sc[i] | ((unsigned)(dc[i] & 255) << 17);
        }
    }
}

__global__ __launch_bounds__(256) void k_bucket(const unsigned* __restrict__ packed,
                                                const int* __restrict__ bkt_cur,
                                                int* __restrict__ csr, int* __restrict__ deg,
                                                int* __restrict__ rp,
                                                int* __restrict__ dcnt) {
    __shared__ int cnt[256];
    __shared__ int off[256];
    __shared__ int dh[64];
    int b = blockIdx.x, t = threadIdx.x;
    int base = b * CAP, end = bkt_cur[b];
    cnt[t] = 0;
    if (t < 64) dh[t] = 0;
    __syncthreads();
    for (int i = base + t; i < end; i += 256) {
        unsigned u = packed[i];
        atomicAdd(&cnt[u >> 17], 1);
    }
    __syncthreads();
    int v = cnt[t];
    int node = b * 256 + t;
    if (node < NN) atomicAdd(&dh[v < 63 ? v : 63], 1);
    off[t] = v;
    __syncthreads();
    for (int o = 1; o < 256; o <<= 1) {
        int u = (t >= o) ? off[t - o] : 0;
        __syncthreads();
        off[t] += u;
        __syncthreads();
    }
    int excl = off[t] - v;                 // exclusive prefix within bucket
    if (node < NN) {
        deg[node] = v;
        rp[node] = base + excl;
    }
    cnt[t] = base + excl;                  // reuse as scatter cursor
    __syncthreads();
    for (int i = base + t; i < end; i += 256) {
        unsigned u = packed[i];
        int p = atomicAdd(&cnt[u >> 17], 1);
        csr[p] = (int)(u & 0x1FFFFu);
    }
    if (t < 64 && dh[t]) atomicAdd(&dcnt[t], dh[t]);
}

__global__ void k_dscan(const int* __restrict__ dcnt, int* __restrict__ dcur) {
    __shared__ int s[64];
    int t = threadIdx.x;
    int v = dcnt[t];
    s[t] = v;
    __syncthreads();
    for (int o = 1; o < 64; o <<= 1) {
        int u = (t >= o) ? s[t - o] : 0;
        __syncthreads();
        s[t] += u;
        __syncthreads();
    }
    dcur[t] = s[t] - v;
}

__global__ __launch_bounds__(256) void k_dperm(const int* __restrict__ deg,
                                               const int* __restrict__ rp,
                                               int* __restrict__ dcur,
                                               uint2* __restrict__ perm) {
    __shared__ int lc[64];
    __shared__ int gb[64];
    int t = threadIdx.x;
    if (t < 64) lc[t] = 0;
    __syncthreads();
    int node = blockIdx.x * 256 + t;
    int bin = 0, r = 0, d = 0;
    bool ok = node < NN;
    if (ok) {
        d = deg[node];
        bin = d < 63 ? d : 63;
        r = atomicAdd(&lc[bin], 1);
    }
    __syncthreads();
    if (t < 64) gb[t] = lc[t] ? atomicAdd(&dcur[t], lc[t]) : 0;
    __syncthreads();
    if (ok) perm[gb[bin] + r] = make_uint2((unsigned)node | ((unsigned)d << 17),
                                           (unsigned)rp[node]);
}

// ---------------- gather layer 1 (fp8): agg1b[n] = bf16(mean x[s]) ----------------
__global__ __launch_bounds__(256) void k_agg1(
    const uint4* __restrict__ xb8, const int* __restrict__ csr,
    const uint2* __restrict__ perm, uint4* __restrict__ agg1b) {
    int t = threadIdx.x;
    int lane = t & 63;
    int grp = lane >> 2, f = lane & 3;
    int slot = blockIdx.x * 64 + (t >> 6) * 16 + grp;
    bool ok = slot < NN;
    uint2 pn = ok ? perm[slot] : make_uint2(0u, 0u);
    int node = (int)(pn.x & NMSK);
    int len = ok ? (int)(pn.x >> 17) : 0;
    const int* cp = csr + pn.y;
    f32x2 c[8];
#pragma unroll
    for (int k = 0; k < 8; k++) c[k] = (f32x2){0.f, 0.f};
    int s0 = cp[0] & NMSK, s1 = cp[1] & NMSK, s2 = cp[2] & NMSK, s3 = cp[3] & NMSK;
    int j = 0;
    while (j + 3 < len) {
        int n0 = cp[j + 4] & NMSK, n1 = cp[j + 5] & NMSK;
        int n2 = cp[j + 6] & NMSK, n3 = cp[j + 7] & NMSK;
        uint4 u0 = xb8[s0 * 4 + f];
        uint4 u1 = xb8[s1 * 4 + f];
        uint4 u2 = xb8[s2 * 4 + f];
        uint4 u3 = xb8[s3 * 4 + f];
        c[0] += cvt2_lo(u0.x); c[1] += cvt2_hi(u0.x); c[2] += cvt2_lo(u0.y); c[3] += cvt2_hi(u0.y);
        c[4] += cvt2_lo(u0.z); c[5] += cvt2_hi(u0.z); c[6] += cvt2_lo(u0.w); c[7] += cvt2_hi(u0.w);
        c[0] += cvt2_lo(u1.x); c[1] += cvt2_hi(u1.x); c[2] += cvt2_lo(u1.y); c[3] += cvt2_hi(u1.y);
        c[4] += cvt2_lo(u1.z); c[5] += cvt2_hi(u1.z); c[6] += cvt2_lo(u1.w); c[7] += cvt2_hi(u1.w);
        c[0] += cvt2_lo(u2.x); c[1] += cvt2_hi(u2.x); c[2] += cvt2_lo(u2.y); c[3] += cvt2_hi(u2.y);
        c[4] += cvt2_lo(u2.z); c[5] += cvt2_hi(u2.z); c[6] += cvt2_lo(u2.w); c[7] += cvt2_hi(u2.w);
        c[0] += cvt2_lo(u3.x); c[1] += cvt2_hi(u3.x); c[2] += cvt2_lo(u3.y); c[3] += cvt2_hi(u3.y);
        c[4] += cvt2_lo(u3.z); c[5] += cvt2_hi(u3.z); c[6] += cvt2_lo(u3.w); c[7] += cvt2_hi(u3.w);
        j += 4; s0 = n0; s1 = n1; s2 = n2; s3 = n3;
    }
    while (j < len) {
        uint4 u = xb8[s0 * 4 + f];
        c[0] += cvt2_lo(u.x); c[1] += cvt2_hi(u.x); c[2] += cvt2_lo(u.y); c[3] += cvt2_hi(u.y);
        c[4] += cvt2_lo(u.z); c[5] += cvt2_hi(u.z); c[6] += cvt2_lo(u.w); c[7] += cvt2_hi(u.w);
        s0 = s1; s1 = s2; s2 = s3; ++j;
    }
    float ic = 1.0f / fmaxf((float)len, 1.0f);
    uint4 o0, o1;
    o0.x = (unsigned)f2bf(c[0][0] * ic) | ((unsigned)f2bf(c[0][1] * ic) << 16);
    o0.y = (unsigned)f2bf(c[1][0] * ic) | ((unsigned)f2bf(c[1][1] * ic) << 16);
    o0.z = (unsigned)f2bf(c[2][0] * ic) | ((unsigned)f2bf(c[2][1] * ic) << 16);
    o0.w = (unsigned)f2bf(c[3][0] * ic) | ((unsigned)f2bf(c[3][1] * ic) << 16);
    o1.x = (unsigned)f2bf(c[4][0] * ic) | ((unsigned)f2bf(c[4][1] * ic) << 16);
    o1.y = (unsigned)f2bf(c[5][0] * ic) | ((unsigned)f2bf(c[5][1] * ic) << 16);
    o1.z = (unsigned)f2bf(c[6][0] * ic) | ((unsigned)f2bf(c[6][1] * ic) << 16);
    o1.w = (unsigned)f2bf(c[7][0] * ic) | ((unsigned)f2bf(c[7][1] * ic) << 16);
    if (ok) {
        agg1b[node * 8 + f * 2] = o0;
        agg1b[node * 8 + f * 2 + 1] = o1;
    }
}

// ---------------- gather layer 2 (fp8, permuted cols) + BN fold ----------------
__global__ __launch_bounds__(256) void k_agg2(
    const uint4* __restrict__ h1f8, const int* __restrict__ csr,
    const float* __restrict__ statsp, const uint2* __restrict__ perm,
    uint4* __restrict__ a2b) {
    int t = threadIdx.x;
    int lane = t & 63;
    int grp = lane >> 3, f = lane & 7;
    int slot = blockIdx.x * 32 + (t >> 6) * 8 + grp;   // NN % 32 == 0
    uint2 pn = perm[slot];
    int node = (int)(pn.x & NMSK);
    int len = (int)(pn.x >> 17);
    const int* cp = csr + pn.y;
    f32x2 c[8];
#pragma unroll
    for (int k = 0; k < 8; k++) c[k] = (f32x2){0.f, 0.f};
    int s0 = cp[0] & NMSK, s1 = cp[1] & NMSK, s2 = cp[2] & NMSK, s3 = cp[3] & NMSK;
    int j = 0;
    while (j + 3 < len) {
        int n0 = cp[j + 4] & NMSK, n1 = cp[j + 5] & NMSK;
        int n2 = cp[j + 6] & NMSK, n3 = cp[j + 7] & NMSK;
        uint4 u0 = h1f8[s0 * 8 + f];
        uint4 u1 = h1f8[s1 * 8 + f];
        uint4 u2 = h1f8[s2 * 8 + f];
        uint4 u3 = h1f8[s3 * 8 + f];
        c[0] += cvt2_lo(u0.x); c[1] += cvt2_hi(u0.x); c[2] += cvt2_lo(u0.y); c[3] += cvt2_hi(u0.y);
        c[4] += cvt2_lo(u0.z); c[5] += cvt2_hi(u0.z); c[6] += cvt2_lo(u0.w); c[7] += cvt2_hi(u0.w);
        c[0] += cvt2_lo(u1.x); c[1] += cvt2_hi(u1.x); c[2] += cvt2_lo(u1.y); c[3] += cvt2_hi(u1.y);
        c[4] += cvt2_lo(u1.z); c[5] += cvt2_hi(u1.z); c[6] += cvt2_lo(u1.w); c[7] += cvt2_hi(u1.w);
        c[0] += cvt2_lo(u2.x); c[1] += cvt2_hi(u2.x); c[2] += cvt2_lo(u2.y); c[3] += cvt2_hi(u2.y);
        c[4] += cvt2_lo(u2.z); c[5] += cvt2_hi(u2.z); c[6] += cvt2_lo(u2.w); c[7] += cvt2_hi(u2.w);
        c[0] += cvt2_lo(u3.x); c[1] += cvt2_hi(u3.x); c[2] += cvt2_lo(u3.y); c[3] += cvt2_hi(u3.y);
        c[4] += cvt2_lo(u3.z); c[5] += cvt2_hi(u3.z); c[6] += cvt2_lo(u3.w); c[7] += cvt2_hi(u3.w);
        j += 4; s0 = n0; s1 = n1; s2 = n2; s3 = n3;
    }
    while (j < len) {
        uint4 u = h1f8[s0 * 8 + f];
        c[0] += cvt2_lo(u.x); c[1] += cvt2_hi(u.x); c[2] += cvt2_lo(u.y); c[3] += cvt2_hi(u.y);
        c[4] += cvt2_lo(u.z); c[5] += cvt2_hi(u.z); c[6] += cvt2_lo(u.w); c[7] += cvt2_hi(u.w);
        s0 = s1; s1 = s2; s2 = s3; ++j;
    }
    float ic = 1.0f / fmaxf((float)len, 1.0f);
    float hv = (len > 0) ? 1.0f : 0.0f;
    const float4* sc4 = (const float4*)statsp;
    const float4* sh4 = (const float4*)(statsp + 128);
    float v[16];
#pragma unroll
    for (int q = 0; q < 4; q++) {
        float4 sc = sc4[f * 4 + q];
        float4 sh = sh4[f * 4 + q];
        v[q * 4 + 0] = c[q * 2][0] * ic * sc.x + sh.x * hv;
        v[q * 4 + 1] = c[q * 2][1] * ic * sc.y + sh.y * hv;
        v[q * 4 + 2] = c[q * 2 + 1][0] * ic * sc.z + sh.z * hv;
        v[q * 4 + 3] = c[q * 2 + 1][1] * ic * sc.w + sh.w * hv;
    }
    uint4 o0, o1;
    o0.x = (unsigned)f2bf(v[0]) | ((unsigned)f2bf(v[1]) << 16);
    o0.y = (unsigned)f2bf(v[2]) | ((unsigned)f2bf(v[3]) << 16);
    o0.z = (unsigned)f2bf(v[4]) | ((unsigned)f2bf(v[5]) << 16);
    o0.w = (unsigned)f2bf(v[6]) | ((unsigned)f2bf(v[7]) << 16);
    o1.x = (unsigned)f2bf(v[8]) | ((unsigned)f2bf(v[9]) << 16);
    o1.y = (unsigned)f2bf(v[10]) | ((unsigned)f2bf(v[11]) << 16);
    o1.z = (unsigned)f2bf(v[12]) | ((unsigned)f2bf(v[13]) << 16);
    o1.w = (unsigned)f2bf(v[14]) | ((unsigned)f2bf(v[15]) << 16);
    a2b[node * 16 + f * 2] = o0;
    a2b[node * 16 + f * 2 + 1] = o1;
}

// ---------------- layer 1 MFMA (proven form + next-tile A prefetch) ----
__global__ __launch_bounds__(256, 3) void k_gemm1(
    const uint4* __restrict__ agg1b, const uint4* __restrict__ xb,
    const uint4* __restrict__ W1T, const float* __restrict__ b1l,
    uint4* __restrict__ h1b, uint2* __restrict__ h1f8, float* __restrict__ part) {
    __shared__ unsigned short Wsm[128 * LDA];  // 34816 B
    __shared__ unsigned short Asm[64 * LDA];   // 17408 B
    __shared__ float cs[128], cq[128];
    const int t = threadIdx.x;
    const int w = t >> 6, lane = t & 63, quad = lane >> 4, l15 = lane & 15;
    if (t < 128) { cs[t] = 0.f; cq[t] = 0.f; }
    {   // stage W1T once (row=256B=16 uint4)
        int r = t >> 1, h = t & 1;
#pragma unroll
        for (int i = 0; i < 8; i++) {
            uint4 v = W1T[r * 16 + h * 8 + i];
            *(uint4*)&Wsm[r * LDA + h * 64 + i * 8] = v;
        }
    }
    float bias[8];
#pragma unroll
    for (int nt = 0; nt < 8; nt++) bias[nt] = b1l[nt * 16 + l15];
    float colsum[8] = {0, 0, 0, 0, 0, 0, 0, 0};
    float colsq[8]  = {0, 0, 0, 0, 0, 0, 0, 0};
    const int arow = 16 * w + l15;          // this lane's A-fragment row
    __syncthreads();                        // W staged, cs/cq init

    Q16 af[4];
    {
        const int base0 = blockIdx.x * 64;
        const int valid0 = (NN - base0 < 64) ? (NN - base0) : 64;
        const int gm0 = base0 + arow;
        const bool ok0 = arow < valid0;
#pragma unroll
        for (int kc = 0; kc < 2; kc++)
            af[kc].q = ok0 ? agg1b[gm0 * 8 + kc * 4 + quad] : make_uint4(0, 0, 0, 0);
#pragma unroll
        for (int kc = 0; kc < 2; kc++)
            af[2 + kc].q = ok0 ? xb[gm0 * 8 + kc * 4 + quad] : make_uint4(0, 0, 0, 0);
    }

    for (int g = blockIdx.x; g < NT1; g += gridDim.x) {
        const int base = g * 64;
        const int valid = (NN - base < 64) ? (NN - base) : 64;
        f32x4 acc[8];
#pragma unroll
        for (int nt = 0; nt < 8; nt++) acc[nt] = (f32x4){bias[nt], bias[nt], bias[nt], bias[nt]};
#pragma unroll
        for (int kc = 0; kc < 4; kc++) {
#pragma unroll
            for (int nt = 0; nt < 8; nt++) {
                s16x8 bf = *(const s16x8*)&Wsm[(nt * 16 + l15) * LDA + kc * 32 + quad * 8];
                acc[nt] = __builtin_amdgcn_mfma_f32_16x16x32_bf16(af[kc].v, bf, acc[nt], 0, 0, 0);
            }
        }
        {   // prefetch next tile's A-fragments (af dead after MFMA)
            const int gn = g + gridDim.x;
            const bool okg = gn < NT1;
            const int basen = okg ? gn * 64 : 0;
            const int validn = (NN - basen < 64) ? (NN - basen) : 64;
            const int gmn = basen + arow;
            const bool okn = okg && (arow < validn);
#pragma unroll
            for (int kc = 0; kc < 2; kc++)
                af[kc].q = okn ? agg1b[gmn * 8 + kc * 4 + quad] : make_uint4(0, 0, 0, 0);
#pragma unroll
            for (int kc = 0; kc < 2; kc++)
                af[2 + kc].q = okn ? xb[gmn * 8 + kc * 4 + quad] : make_uint4(0, 0, 0, 0);
        }
        // epilogue: norm+relu+stats; bf16 into Asm (std cols); fp8 direct (permuted)
        float ssr[4] = {0, 0, 0, 0};
#pragma unroll
        for (int nt = 0; nt < 8; nt++)
#pragma unroll
            for (int r = 0; r < 4; r++) ssr[r] += acc[nt][r] * acc[nt][r];
#pragma unroll
        for (int r = 0; r < 4; r++) {
            ssr[r] += __shfl_xor(ssr[r], 1); ssr[r] += __shfl_xor(ssr[r], 2);
            ssr[r] += __shfl_xor(ssr[r], 4); ssr[r] += __shfl_xor(ssr[r], 8);
        }
#pragma unroll
        for (int r = 0; r < 4; r++) {
            int mrow = 16 * w + quad * 4 + r;
            float iv = 1.0f / fmaxf(sqrtf(ssr[r]), 1e-12f);
            bool okr = mrow < valid;
            float v[8];
#pragma unroll
            for (int nt = 0; nt < 8; nt++) {
                float vv = fmaxf(acc[nt][r] * iv, 0.f);
                if (!okr) vv = 0.f;
                v[nt] = vv;
                colsum[nt] += vv;
                colsq[nt] += vv * vv;
                Asm[mrow * LDA + nt * 16 + l15] = f2bf(vv);
            }
            if (okr) {
                uint2 o;
                o.x = pk_fp8x4(v[0], v[1], v[2], v[3]);
                o.y = pk_fp8x4(v[4], v[5], v[6], v[7]);
                h1f8[(base + mrow) * 16 + l15] = o;   // permuted col' = l15*8+nt
            }
        }
        __syncthreads();
        {   // coalesced h1b store (row=256B=16 uint4), STANDARD layout
            int m = t >> 2, p = t & 3;
            if (m < valid) {
                int gm2 = base + m;
#pragma unroll
                for (int i = 0; i < 4; i++) {
                    uint4 v = *(const uint4*)&Asm[m * LDA + p * 32 + i * 8];
                    h1b[gm2 * 16 + p * 4 + i] = v;
                }
            }
        }
        __syncthreads();  // readback done before next epilogue overwrites Asm
    }
    __syncthreads();
#pragma unroll
    for (int nt = 0; nt < 8; nt++) {
        atomicAdd(&cs[nt * 16 + l15], colsum[nt]);
        atomicAdd(&cq[nt * 16 + l15], colsq[nt]);
    }
    __syncthreads();
    if (t < 128) {
        part[blockIdx.x * 256 + t] = cs[t];
        part[blockIdx.x * 256 + 128 + t] = cq[t];
    }
}

// ---------------- BN finalize: stats + permuted copy ----------------
__global__ void k_bnfin(const float* __restrict__ part, const float* __restrict__ gamma,
                        const float* __restrict__ beta, float* __restrict__ stats) {
    int t = threadIdx.x;  // 128 (channel)
    float s = 0.f, q = 0.f;
    for (int b = 0; b < PART_BLOCKS; b++) {
        s += part[b * 256 + t];
        q += part[b * 256 + 128 + t];
    }
    float mean = s / (float)NN;
    float var = q / (float)NN - mean * mean;
    float sc = gamma[t] * rsqrtf(var + 1e-5f);
    float sh = beta[t] - mean * sc;
    stats[t] = sc;
    stats[128 + t] = sh;
    int cp = (t & 15) * 8 + (t >> 4);   // permuted position of channel t
    stats[256 + cp] = sc;
    stats[384 + cp] = sh;
}

// ---------------- W2 fixup: fold BN scale into lin_r weights, shift into bias ----
__global__ void k_wfix(const float* __restrict__ w2r, const float* __restrict__ stats,
                       const float* __restrict__ b2l,
                       unsigned short* __restrict__ W2T, float* __restrict__ bias2) {
    __shared__ float sb[128];
    int n = blockIdx.x;       // 128 (output channel)
    int k = threadIdx.x;      // 128 (std K position = h1 channel)
    float wv = w2r[k * 128 + n];
    W2T[n * 256 + 128 + k] = f2bf(wv * stats[k]);
    sb[k] = stats[128 + k] * wv;                    // sh[k] * w2r[k][n]
    __syncthreads();
    for (int o = 64; o > 0; o >>= 1) {
        if (k < o) sb[k] += sb[k + o];
        __syncthreads();
    }
    if (k == 0) bias2[n] = b2l[n] + sb[0];
}

// ---------------- layer 2 MFMA (K=256) + L2norm + FC: 1024-thread / 256-row tiles ----
// 16 waves/block = 4 waves/SIMD (vs 2 at 512 threads) — doubles latency hiding at the
// same 1 block/CU. LDS: WsmF 67.6K + Asm(256 rows) 69.6K + wfc 4.3K = 141.6K <= 160K.
// Structure (barriers, prefetch, epilogue, FC) identical per wave.
__global__ __launch_bounds__(1024) void k_gemm2(
    const uint4* __restrict__ a2b, const uint4* __restrict__ h1b,
    const uint4* __restrict__ W2T, const float* __restrict__ bias2,
    const uint4* __restrict__ wfcT, const float* __restrict__ bfc,
    float* __restrict__ out) {
    __shared__ unsigned short WsmF[128 * LDW];   // 67584 B (full W2T [N=128][K=256])
    __shared__ unsigned short Asm[256 * LDA];    // 69632 B (h2 for FC redistribution)
    __shared__ unsigned short wfcsm[16 * LDA];   // 4352 B
    const int t = threadIdx.x;
    const int w = t >> 6, lane = t & 63, quad = lane >> 4, l15 = lane & 15;

    {   // full W2T: 4096 uint4 / 1024 threads = 4 each; row r, 8 segs of 4 uint4
        int r = t >> 3, seg = t & 7;
#pragma unroll
        for (int i = 0; i < 4; i++) {
            uint4 v = W2T[r * 32 + seg * 4 + i];
            *(uint4*)&WsmF[r * LDW + (seg * 4 + i) * 8] = v;
        }
    }
    if (t < 256) {   // wfcT: 256 uint4
        int n = t >> 4, p = t & 15;
        *(uint4*)&wfcsm[n * LDA + p * 8] = wfcT[n * 16 + p];
    }
    float bias[8];
#pragma unroll
    for (int nt = 0; nt < 8; nt++) bias[nt] = bias2[nt * 16 + l15];
    const float fb = bfc[l15];
    const int arow = 16 * w + l15;          // 0..255
    __syncthreads();

    Q16 af[8];
    {
        const int base0 = blockIdx.x * 256;
        const int valid0 = (NN - base0 < 256) ? (NN - base0) : 256;
        const int gm0 = base0 + arow;
        const bool ok0 = arow < valid0;
#pragma unroll
        for (int kc = 0; kc < 4; kc++)
            af[kc].q = ok0 ? a2b[gm0 * 16 + kc * 4 + quad] : make_uint4(0, 0, 0, 0);
#pragma unroll
        for (int kc = 0; kc < 4; kc++)
            af[4 + kc].q = ok0 ? h1b[gm0 * 16 + kc * 4 + quad] : make_uint4(0, 0, 0, 0);
    }

    for (int g = blockIdx.x; g < NT2; g += gridDim.x) {
        const int base = g * 256;
        const int valid = (NN - base < 256) ? (NN - base) : 256;

        f32x4 acc[8];
#pragma unroll
        for (int nt = 0; nt < 8; nt++) acc[nt] = (f32x4){bias[nt], bias[nt], bias[nt], bias[nt]};
#pragma unroll
        for (int kc = 0; kc < 8; kc++) {
#pragma unroll
            for (int nt = 0; nt < 8; nt++) {
                s16x8 bf = *(const s16x8*)&WsmF[(nt * 16 + l15) * LDW + kc * 32 + quad * 8];
                acc[nt] = __builtin_amdgcn_mfma_f32_16x16x32_bf16(af[kc].v, bf, acc[nt], 0, 0, 0);
            }
        }
        {   // prefetch next tile's A-fragments (af dead after MFMA)
            const int gn = g + gridDim.x;
            const bool okg = gn < NT2;
            const int basen = okg ? gn * 256 : 0;
            const int validn = (NN - basen < 256) ? (NN - basen) : 256;
            const int gmn = basen + arow;
            const bool okn = okg && (arow < validn);
#pragma unroll
            for (int kc = 0; kc < 4; kc++)
                af[kc].q = okn ? a2b[gmn * 16 + kc * 4 + quad] : make_uint4(0, 0, 0, 0);
#pragma unroll
            for (int kc = 0; kc < 4; kc++)
                af[4 + kc].q = okn ? h1b[gmn * 16 + kc * 4 + quad] : make_uint4(0, 0, 0, 0);
        }

        // epilogue: L2 norm, h2 -> Asm (standard col positions)
        float ssr[4] = {0, 0, 0, 0};
#pragma unroll
        for (int nt = 0; nt < 8; nt++)
#pragma unroll
            for (int r = 0; r < 4; r++) ssr[r] += acc[nt][r] * acc[nt][r];
#pragma unroll
        for (int r = 0; r < 4; r++) {
            ssr[r] += __shfl_xor(ssr[r], 1); ssr[r] += __shfl_xor(ssr[r], 2);
            ssr[r] += __shfl_xor(ssr[r], 4); ssr[r] += __shfl_xor(ssr[r], 8);
        }
#pragma unroll
        for (int r = 0; r < 4; r++) {
            int mrow = 16 * w + quad * 4 + r;
            float iv = 1.0f / fmaxf(sqrtf(ssr[r]), 1e-12f);
#pragma unroll
            for (int nt = 0; nt < 8; nt++) {
                Asm[mrow * LDA + nt * 16 + l15] = f2bf(acc[nt][r] * iv);
            }
        }
        __syncthreads();   // h2 complete
        // FC: 16x16 tile per wave, K=128
        f32x4 a2 = (f32x4){fb, fb, fb, fb};
#pragma unroll
        for (int kc = 0; kc < 4; kc++) {
            s16x8 af2 = *(const s16x8*)&Asm[arow * LDA + kc * 32 + quad * 8];
            s16x8 bf2 = *(const s16x8*)&wfcsm[l15 * LDA + kc * 32 + quad * 8];
            a2 = __builtin_amdgcn_mfma_f32_16x16x32_bf16(af2, bf2, a2, 0, 0, 0);
        }
#pragma unroll
        for (int r = 0; r < 4; r++) {
            int mrow = 16 * w + quad * 4 + r;
            if (mrow < valid) out[(base + mrow) * 16 + l15] = a2[r];
        }
        __syncthreads();   // FC reads done before next tile overwrites Asm
    }
}

extern "C" void kernel_launch(void* const* d_in, const int* in_sizes, int n_in,
                              void* d_out, int out_size, void* d_ws, size_t ws_size,
                              hipStream_t stream) {
    const float* x     = (const float*)d_in[0];
    const int*   ei    = (const int*)d_in[1];
    const float* w1l   = (const float*)d_in[2];
    const float* b1l   = (const float*)d_in[3];
    const float* w1r   = (const float*)d_in[4];
    const float* gamma = (const float*)d_in[5];
    const float* beta  = (const float*)d_in[6];
    const float* w2l   = (const float*)d_in[7];
    const float* b2l   = (const float*)d_in[8];
    const float* w2r   = (const float*)d_in[9];
    const float* wfc   = (const float*)d_in[10];
    const float* bfc   = (const float*)d_in[11];
    float* out = (float*)d_out;

    float* W = (float*)d_ws;
    int* bkt_cur  = (int*)(W + OFS_BKT) + 1024;   // [512] (pre-init by k_init to b*CAP)
    int* dcnt     = (int*)(W + OFS_BKT) + 1536;   // [64]
    int* dcur     = (int*)(W + OFS_BKT) + 1600;   // [64]
    int* deg   = (int*)(W + OFS_DEG);
    int* rp    = (int*)(W + OFS_RP);
    float* bias2 = W + OFS_BSUM;                  // [128] fp32
    uint2* perm = (uint2*)(W + OFS_RANK);         // 2*NN words (fat records)
    int* csr   = (int*)(W + OFS_CSR);             // capacity layout: NBK*CAP words
    unsigned* xb   = (unsigned*)(W + OFS_XB);
    unsigned* xb8  = (unsigned*)(W + OFS_XB8);
    unsigned* a1b  = (unsigned*)(W + OFS_A1B);
    unsigned* h1b  = (unsigned*)(W + OFS_H1B);
    unsigned* h1f8 = (unsigned*)(W + OFS_H1F8);
    unsigned* a2b  = (unsigned*)(W + OFS_A2B);
    unsigned* packed = (unsigned*)(W + OFS_A2B);  // NBK*CAP words; dead before k_agg2 writes a2b
    unsigned short* W1T  = (unsigned short*)(W + OFS_W1T);
    unsigned short* W2T  = (unsigned short*)(W + OFS_W2T);
    unsigned short* wfcT = (unsigned short*)(W + OFS_WFCT);
    float* stats = W + OFS_STATS;          // [sc|sh|sc'|sh'] (512)
    float* part  = W + OFS_PART;

    k_init<<<CAST_BLOCKS + PREP_BLOCKS + 1, 256, 0, stream>>>(
        (const float4*)x, (uint2*)xb, xb8, w1l, w1r, w2l, w2r, wfc, W1T, W2T, wfcT,
        bkt_cur, dcnt);
    k_part  <<<NPB, 256, 0, stream>>>(ei, bkt_cur, packed);
    k_bucket<<<NBK, 256, 0, stream>>>(packed, bkt_cur, csr, deg, rp, dcnt);
    k_dscan <<<1, 64, 0, stream>>>(dcnt, dcur);
    k_dperm <<<NBK, 256, 0, stream>>>(deg, rp, dcur, perm);

    k_agg1 <<<(NN + 63) / 64, 256, 0, stream>>>((const uint4*)xb8, csr, perm, (uint4*)a1b);
    k_gemm1<<<PART_BLOCKS, 256, 0, stream>>>((const uint4*)a1b, (const uint4*)xb,
                                             (const uint4*)W1T, b1l, (uint4*)h1b,
                                             (uint2*)h1f8, part);
    k_bnfin<<<1, 128, 0, stream>>>(part, gamma, beta, stats);
    k_wfix <<<128, 128, 0, stream>>>(w2r, stats, b2l, W2T, bias2);
    k_agg2 <<<NN / 32, 256, 0, stream>>>((const uint4*)h1f8, csr, stats + 256, perm,
                                         (uint4*)a2b);
    k_gemm2<<<256, 1024, 0, stream>>>((const uint4*)a2b, (const uint4*)h1b,
                                      (const uint4*)W2T, bias2, (const uint4*)wfcT,
                                      bfc, out);
}